// Round 1
// baseline (1258.109 us; speedup 1.0000x reference)
//
#include <hip/hip_runtime.h>
#include <math.h>

#define N_NODES 100000
#define N_EDGES 1200000
#define E_TOT   1300000   // + self loops
#define N_GRAPHS 1000
#define HID 64

__device__ __forceinline__ float wave_reduce_sum(float v) {
    #pragma unroll
    for (int off = 32; off > 0; off >>= 1)
        v += __shfl_xor(v, off, 64);
    return v;
}

// Orderable-uint encoding for float atomicMax. Monotone: f1<f2 <=> enc(f1)<enc(f2).
// All encodings > 0, so memset-0 acts as the -inf identity.
__device__ __forceinline__ unsigned enc_f(float f) {
    unsigned u = __float_as_uint(f);
    return (f >= 0.f) ? (u | 0x80000000u) : ~u;
}
__device__ __forceinline__ float dec_f(unsigned u) {
    return (u & 0x80000000u) ? __uint_as_float(u & 0x7fffffffu) : __uint_as_float(~u);
}

// c = relu(LN(climber) @ W_c + b_c)    grid=N_GRAPHS, block=64
__global__ void k_climber(const float* __restrict__ climber,
                          const float* __restrict__ ln_g, const float* __restrict__ ln_b,
                          const float* __restrict__ W_c, const float* __restrict__ b_c,
                          float* __restrict__ c) {
    int g = blockIdx.x;
    int j = threadIdx.x;
    float v[6];
    float mu = 0.f;
    #pragma unroll
    for (int k = 0; k < 6; k++) { v[k] = climber[g*6+k]; mu += v[k]; }
    mu *= (1.f/6.f);
    float var = 0.f;
    #pragma unroll
    for (int k = 0; k < 6; k++) { float d = v[k]-mu; var += d*d; }
    var *= (1.f/6.f);
    float rs = rsqrtf(var + 1e-5f);
    float acc = b_c[j];
    #pragma unroll
    for (int k = 0; k < 6; k++) {
        float cn = (v[k]-mu)*rs*ln_g[k] + ln_b[k];
        acc += cn * W_c[k*64+j];
    }
    c[g*64+j] = fmaxf(acc, 0.f);
}

// gb{1,2} = c @ Wf{1,2} + bf{1,2}      grid=(N_GRAPHS,2), block=128
__global__ void k_film_coef(const float* __restrict__ c,
                            const float* __restrict__ Wf1, const float* __restrict__ bf1,
                            const float* __restrict__ Wf2, const float* __restrict__ bf2,
                            float* __restrict__ gb1, float* __restrict__ gb2) {
    int g = blockIdx.x;
    const float* Wf = blockIdx.y ? Wf2 : Wf1;
    const float* bf = blockIdx.y ? bf2 : bf1;
    float*       gb = blockIdx.y ? gb2 : gb1;
    int j = threadIdx.x;
    float acc = bf[j];
    #pragma unroll 8
    for (int k = 0; k < 64; k++)
        acc += c[g*64+k] * Wf[k*128+j];
    gb[g*128+j] = acc;
}

// h = film1(x[:, :6] @ W_in + b_in)    one wave per node
__global__ void k_node_init(const float* __restrict__ x, const int* __restrict__ batch,
                            const float* __restrict__ W_in, const float* __restrict__ b_in,
                            const float* __restrict__ gb1, float* __restrict__ h) {
    int i = (blockIdx.x * blockDim.x + threadIdx.x) >> 6;
    int j = threadIdx.x & 63;
    if (i >= N_NODES) return;
    float acc = b_in[j];
    #pragma unroll
    for (int k = 0; k < 6; k++)
        acc += x[i*8+k] * W_in[k*64+j];
    int g = batch[i];
    h[i*64+j] = acc * (1.f + gb1[g*128+j]) + gb1[g*128+64+j];
}

// z = h @ Wg ; es = z@a_src ; ed = z@a_dst   one wave per node, Wg in LDS
__global__ void k_gat_z(const float* __restrict__ h, const float* __restrict__ Wg,
                        const float* __restrict__ a_src, const float* __restrict__ a_dst,
                        float* __restrict__ z, float* __restrict__ es, float* __restrict__ ed) {
    __shared__ float Wl[64*64];
    for (int t = threadIdx.x; t < 4096; t += blockDim.x) Wl[t] = Wg[t];
    __syncthreads();
    int i = (blockIdx.x * blockDim.x + threadIdx.x) >> 6;
    int j = threadIdx.x & 63;
    if (i >= N_NODES) return;
    float acc = 0.f;
    #pragma unroll 8
    for (int k = 0; k < 64; k++)
        acc += h[i*64+k] * Wl[k*64+j];
    z[i*64+j] = acc;
    float ps = wave_reduce_sum(acc * a_src[j]);
    float pd = wave_reduce_sum(acc * a_dst[j]);
    if (j == 0) { es[i] = ps; ed[i] = pd; }
}

// per-edge score + segment max
__global__ void k_edge_max(const int* __restrict__ ei, const float* __restrict__ es,
                           const float* __restrict__ ed, float* __restrict__ e_edge,
                           unsigned* __restrict__ m_u) {
    int e = blockIdx.x * blockDim.x + threadIdx.x;
    if (e >= E_TOT) return;
    int src, dst;
    if (e < N_EDGES) { src = ei[e]; dst = ei[N_EDGES + e]; }
    else             { src = dst = e - N_EDGES; }
    float v = es[src] + ed[dst];
    v = (v > 0.f) ? v : 0.2f * v;      // leaky_relu 0.2
    e_edge[e] = v;
    atomicMax(&m_u[dst], enc_f(v));
}

// ex = exp(e - m[dst]) ; segment sum
__global__ void k_edge_exp(const int* __restrict__ ei, const unsigned* __restrict__ m_u,
                           float* __restrict__ e_edge, float* __restrict__ s) {
    int e = blockIdx.x * blockDim.x + threadIdx.x;
    if (e >= E_TOT) return;
    int dst = (e < N_EDGES) ? ei[N_EDGES + e] : (e - N_EDGES);
    float m = dec_f(m_u[dst]);
    float ex = expf(e_edge[e] - m);
    e_edge[e] = ex;
    atomicAdd(&s[dst], ex);
}

// agg[dst] += alpha * z[src]   one wave per edge, lane = feature
__global__ void k_edge_agg(const int* __restrict__ ei, const float* __restrict__ e_edge,
                           const float* __restrict__ s, const float* __restrict__ z,
                           float* __restrict__ agg) {
    long long t = (long long)blockIdx.x * blockDim.x + threadIdx.x;
    int e = (int)(t >> 6);
    int j = (int)(t & 63);
    if (e >= E_TOT) return;
    int src, dst;
    if (e < N_EDGES) { src = ei[e]; dst = ei[N_EDGES + e]; }
    else             { src = dst = e - N_EDGES; }
    float alpha = e_edge[e] / (s[dst] + 1e-16f);
    atomicAdd(&agg[dst*64+j], alpha * z[src*64+j]);
}

// h = relu(agg + bg) [then film2 if apply_film]
__global__ void k_gat_fin(const float* __restrict__ agg, const float* __restrict__ bg,
                          const int* __restrict__ batch, const float* __restrict__ gb,
                          int apply_film, float* __restrict__ h) {
    int i = (blockIdx.x * blockDim.x + threadIdx.x) >> 6;
    int j = threadIdx.x & 63;
    if (i >= N_NODES) return;
    float v = fmaxf(agg[i*64+j] + bg[j], 0.f);
    if (apply_film) {
        int g = batch[i];
        v = v * (1.f + gb[g*128+j]) + gb[g*128+64+j];
    }
    h[i*64+j] = v;
}

// out = (relu(h@Wc1+bc1)@Wc2+bc2) + 0.03*(relu(flags@Wh1+bh1)@Wh2+bh2)
__global__ void k_head(const float* __restrict__ h, const float* __restrict__ x,
                       const float* __restrict__ Wc1, const float* __restrict__ bc1,
                       const float* __restrict__ Wc2, const float* __restrict__ bc2,
                       const float* __restrict__ Wh1, const float* __restrict__ bh1,
                       const float* __restrict__ Wh2, const float* __restrict__ bh2,
                       float* __restrict__ out) {
    __shared__ float Wl[64*64];
    for (int t = threadIdx.x; t < 4096; t += blockDim.x) Wl[t] = Wc1[t];
    __syncthreads();
    int i = (blockIdx.x * blockDim.x + threadIdx.x) >> 6;
    int j = threadIdx.x & 63;
    if (i >= N_NODES) return;
    float acc = bc1[j];
    #pragma unroll 8
    for (int k = 0; k < 64; k++)
        acc += h[i*64+k] * Wl[k*64+j];
    acc = fmaxf(acc, 0.f);
    float p0 = wave_reduce_sum(acc * Wc2[j*4+0]);
    float p1 = wave_reduce_sum(acc * Wc2[j*4+1]);
    float p2 = wave_reduce_sum(acc * Wc2[j*4+2]);
    float p3 = wave_reduce_sum(acc * Wc2[j*4+3]);
    if (j == 0) {
        float f0 = x[i*8+6], f1 = x[i*8+7];
        float t8[8];
        #pragma unroll
        for (int q = 0; q < 8; q++)
            t8[q] = fmaxf(f0*Wh1[q] + f1*Wh1[8+q] + bh1[q], 0.f);
        float fl[4];
        #pragma unroll
        for (int q = 0; q < 4; q++) {
            float a = bh2[q];
            #pragma unroll
            for (int r = 0; r < 8; r++) a += t8[r]*Wh2[r*4+q];
            fl[q] = a;
        }
        out[i*4+0] = p0 + bc2[0] + 0.03f*fl[0];
        out[i*4+1] = p1 + bc2[1] + 0.03f*fl[1];
        out[i*4+2] = p2 + bc2[2] + 0.03f*fl[2];
        out[i*4+3] = p3 + bc2[3] + 0.03f*fl[3];
    }
}

extern "C" void kernel_launch(void* const* d_in, const int* in_sizes, int n_in,
                              void* d_out, int out_size, void* d_ws, size_t ws_size,
                              hipStream_t stream) {
    const float* x       = (const float*)d_in[0];
    const int*   ei      = (const int*)  d_in[1];
    const int*   batch   = (const int*)  d_in[2];
    const float* climber = (const float*)d_in[3];
    const float* W_in    = (const float*)d_in[4];
    const float* b_in    = (const float*)d_in[5];
    const float* ln_g    = (const float*)d_in[6];
    const float* ln_b    = (const float*)d_in[7];
    const float* W_c     = (const float*)d_in[8];
    const float* b_c     = (const float*)d_in[9];
    const float* Wf1     = (const float*)d_in[10];
    const float* bf1     = (const float*)d_in[11];
    const float* Wf2     = (const float*)d_in[12];
    const float* bf2     = (const float*)d_in[13];
    const float* Wg1     = (const float*)d_in[14];
    const float* as1     = (const float*)d_in[15];
    const float* ad1     = (const float*)d_in[16];
    const float* bg1     = (const float*)d_in[17];
    const float* Wg2     = (const float*)d_in[18];
    const float* as2     = (const float*)d_in[19];
    const float* ad2     = (const float*)d_in[20];
    const float* bg2     = (const float*)d_in[21];
    const float* Wc1     = (const float*)d_in[22];
    const float* bc1     = (const float*)d_in[23];
    const float* Wc2     = (const float*)d_in[24];
    const float* bc2     = (const float*)d_in[25];
    const float* Wh1     = (const float*)d_in[26];
    const float* bh1     = (const float*)d_in[27];
    const float* Wh2     = (const float*)d_in[28];
    const float* bh2     = (const float*)d_in[29];
    float* out = (float*)d_out;
    float* ws  = (float*)d_ws;

    // workspace carve (floats): total ~21.22M floats = 84.9 MB
    float* c      = ws;                    // 64,000
    float* gb1    = c   + 64000;           // 128,000
    float* gb2    = gb1 + 128000;          // 128,000
    float* h      = gb2 + 128000;          // 6,400,000
    float* z      = h   + 6400000;         // 6,400,000
    float* agg    = z   + 6400000;         // 6,400,000
    float* es     = agg + 6400000;         // 100,000
    float* ed     = es  + N_NODES;         // 100,000
    float* s      = ed  + N_NODES;         // 100,000
    unsigned* m_u = (unsigned*)(s + N_NODES);   // 100,000
    float* e_edge = (float*)(m_u + N_NODES);    // 1,300,000

    k_climber<<<N_GRAPHS, 64, 0, stream>>>(climber, ln_g, ln_b, W_c, b_c, c);
    dim3 gB(N_GRAPHS, 2);
    k_film_coef<<<gB, 128, 0, stream>>>(c, Wf1, bf1, Wf2, bf2, gb1, gb2);

    int nodeBlocks = (N_NODES*64 + 255)/256;       // 25000 (4 waves/block, 1 node/wave)
    k_node_init<<<nodeBlocks, 256, 0, stream>>>(x, batch, W_in, b_in, gb1, h);

    int edgeBlocks = (E_TOT + 255)/256;
    long long aggThreads = (long long)E_TOT * 64;
    int aggBlocks = (int)((aggThreads + 255)/256); // 325000

    for (int layer = 0; layer < 2; layer++) {
        const float* Wg  = layer ? Wg2 : Wg1;
        const float* as_ = layer ? as2 : as1;
        const float* ad_ = layer ? ad2 : ad1;
        const float* bg  = layer ? bg2 : bg1;
        hipMemsetAsync(m_u, 0, N_NODES*sizeof(unsigned), stream);
        hipMemsetAsync(s,   0, N_NODES*sizeof(float),    stream);
        hipMemsetAsync(agg, 0, (size_t)N_NODES*HID*sizeof(float), stream);
        k_gat_z  <<<nodeBlocks, 256, 0, stream>>>(h, Wg, as_, ad_, z, es, ed);
        k_edge_max<<<edgeBlocks, 256, 0, stream>>>(ei, es, ed, e_edge, m_u);
        k_edge_exp<<<edgeBlocks, 256, 0, stream>>>(ei, m_u, e_edge, s);
        k_edge_agg<<<aggBlocks, 256, 0, stream>>>(ei, e_edge, s, z, agg);
        k_gat_fin<<<nodeBlocks, 256, 0, stream>>>(agg, bg, batch, gb2,
                                                  layer == 0 ? 1 : 0, h);
    }
    k_head<<<nodeBlocks, 256, 0, stream>>>(h, x, Wc1, bc1, Wc2, bc2,
                                           Wh1, bh1, Wh2, bh2, out);
}

// Round 2
// 995.550 us; speedup vs baseline: 1.2637x; 1.2637x over previous
//
#include <hip/hip_runtime.h>
#include <math.h>

#define N_NODES 100000
#define N_EDGES 1200000
#define N_GRAPHS 1000
#define HID 64

__device__ __forceinline__ float wave_reduce_sum(float v) {
    #pragma unroll
    for (int off = 32; off > 0; off >>= 1)
        v += __shfl_xor(v, off, 64);
    return v;
}

// ---------------- CSR build (once per call, reused by both layers) -----------

__global__ void k_deg(const int* __restrict__ ei, int* __restrict__ deg) {
    int e = blockIdx.x * blockDim.x + threadIdx.x;
    if (e >= N_EDGES) return;
    atomicAdd(&deg[ei[N_EDGES + e]], 1);
}

// single-block exclusive scan over deg[100000] -> rowptr[100001]
__global__ void k_scan(const int* __restrict__ deg, int* __restrict__ rowptr) {
    __shared__ int part[1024];
    const int t = threadIdx.x;
    const int CH = (N_NODES + 1023) / 1024;   // 98
    int base = t * CH;
    int sum = 0;
    for (int k = 0; k < CH; k++) {
        int i = base + k;
        if (i < N_NODES) sum += deg[i];
    }
    part[t] = sum;
    __syncthreads();
    for (int off = 1; off < 1024; off <<= 1) {
        int u = (t >= off) ? part[t - off] : 0;
        __syncthreads();
        part[t] += u;
        __syncthreads();
    }
    int run = part[t] - sum;   // exclusive prefix of this chunk
    for (int k = 0; k < CH; k++) {
        int i = base + k;
        if (i < N_NODES) { rowptr[i] = run; run += deg[i]; }
    }
    if (t == 1023) rowptr[N_NODES] = part[1023];
}

__global__ void k_scatter(const int* __restrict__ ei, const int* __restrict__ rowptr,
                          int* __restrict__ cnt, int* __restrict__ csr_src) {
    int e = blockIdx.x * blockDim.x + threadIdx.x;
    if (e >= N_EDGES) return;
    int src = ei[e], dst = ei[N_EDGES + e];
    int pos = atomicAdd(&cnt[dst], 1);
    csr_src[rowptr[dst] + pos] = src;
}

// ---------------- small dense prologue --------------------------------------

__global__ void k_climber(const float* __restrict__ climber,
                          const float* __restrict__ ln_g, const float* __restrict__ ln_b,
                          const float* __restrict__ W_c, const float* __restrict__ b_c,
                          float* __restrict__ c) {
    int g = blockIdx.x;
    int j = threadIdx.x;
    float v[6];
    float mu = 0.f;
    #pragma unroll
    for (int k = 0; k < 6; k++) { v[k] = climber[g*6+k]; mu += v[k]; }
    mu *= (1.f/6.f);
    float var = 0.f;
    #pragma unroll
    for (int k = 0; k < 6; k++) { float d = v[k]-mu; var += d*d; }
    var *= (1.f/6.f);
    float rs = rsqrtf(var + 1e-5f);
    float acc = b_c[j];
    #pragma unroll
    for (int k = 0; k < 6; k++) {
        float cn = (v[k]-mu)*rs*ln_g[k] + ln_b[k];
        acc += cn * W_c[k*64+j];
    }
    c[g*64+j] = fmaxf(acc, 0.f);
}

__global__ void k_film_coef(const float* __restrict__ c,
                            const float* __restrict__ Wf1, const float* __restrict__ bf1,
                            const float* __restrict__ Wf2, const float* __restrict__ bf2,
                            float* __restrict__ gb1, float* __restrict__ gb2) {
    int g = blockIdx.x;
    const float* Wf = blockIdx.y ? Wf2 : Wf1;
    const float* bf = blockIdx.y ? bf2 : bf1;
    float*       gb = blockIdx.y ? gb2 : gb1;
    int j = threadIdx.x;
    float acc = bf[j];
    #pragma unroll 8
    for (int k = 0; k < 64; k++)
        acc += c[g*64+k] * Wf[k*128+j];
    gb[g*128+j] = acc;
}

__global__ void k_node_init(const float* __restrict__ x, const int* __restrict__ batch,
                            const float* __restrict__ W_in, const float* __restrict__ b_in,
                            const float* __restrict__ gb1, float* __restrict__ h) {
    int i = (blockIdx.x * blockDim.x + threadIdx.x) >> 6;
    int j = threadIdx.x & 63;
    if (i >= N_NODES) return;
    float acc = b_in[j];
    #pragma unroll
    for (int k = 0; k < 6; k++)
        acc += x[i*8+k] * W_in[k*64+j];
    int g = batch[i];
    h[i*64+j] = acc * (1.f + gb1[g*128+j]) + gb1[g*128+64+j];
}

// ---------------- GAT layer -------------------------------------------------

// z = h @ Wg ; es = z@a_src ; ed = z@a_dst   one wave per node, Wg in LDS
__global__ void k_gat_z(const float* __restrict__ h, const float* __restrict__ Wg,
                        const float* __restrict__ a_src, const float* __restrict__ a_dst,
                        float* __restrict__ z, float* __restrict__ es, float* __restrict__ ed) {
    __shared__ float Wl[64*64];
    for (int t = threadIdx.x; t < 4096; t += blockDim.x) Wl[t] = Wg[t];
    __syncthreads();
    int i = (blockIdx.x * blockDim.x + threadIdx.x) >> 6;
    int j = threadIdx.x & 63;
    if (i >= N_NODES) return;
    float acc = 0.f;
    #pragma unroll 8
    for (int k = 0; k < 64; k++)
        acc += h[i*64+k] * Wl[k*64+j];
    z[i*64+j] = acc;
    float ps = wave_reduce_sum(acc * a_src[j]);
    float pd = wave_reduce_sum(acc * a_dst[j]);
    if (j == 0) { es[i] = ps; ed[i] = pd; }
}

// Fused softmax + aggregation + relu + bias (+FiLM), one wave per dst node.
// Self-loop handled analytically (src == dst == i).
__global__ void k_gat_agg(const int* __restrict__ rowptr, const int* __restrict__ csr_src,
                          const float* __restrict__ es, const float* __restrict__ ed,
                          const float* __restrict__ z, const float* __restrict__ bg,
                          const int* __restrict__ batch, const float* __restrict__ gb,
                          int apply_film, float* __restrict__ h) {
    int i = (blockIdx.x * blockDim.x + threadIdx.x) >> 6;
    int j = threadIdx.x & 63;
    if (i >= N_NODES) return;
    int beg = rowptr[i], end = rowptr[i+1];
    float edi = ed[i];

    // self-loop score
    float e_self = es[i] + edi;
    e_self = (e_self > 0.f) ? e_self : 0.2f * e_self;

    // pass A: segment max, lane-parallel over incoming edges
    float m = e_self;
    for (int k = beg + j; k < end; k += 64) {
        float v = es[csr_src[k]] + edi;
        v = (v > 0.f) ? v : 0.2f * v;
        m = fmaxf(m, v);
    }
    #pragma unroll
    for (int off = 32; off > 0; off >>= 1)
        m = fmaxf(m, __shfl_xor(m, off, 64));

    // pass B: serial over edges, feature-parallel accumulate
    float ex = expf(e_self - m);
    float s = ex;
    float acc = ex * z[i*64 + j];
    for (int k = beg; k < end; k++) {
        int src = csr_src[k];
        float v = es[src] + edi;
        v = (v > 0.f) ? v : 0.2f * v;
        float e2 = expf(v - m);
        s += e2;
        acc += e2 * z[src*64 + j];
    }
    float o = acc / (s + 1e-16f);
    o = fmaxf(o + bg[j], 0.f);
    if (apply_film) {
        int g = batch[i];
        o = o * (1.f + gb[g*128+j]) + gb[g*128+64+j];
    }
    h[i*64+j] = o;
}

// ---------------- head ------------------------------------------------------

__global__ void k_head(const float* __restrict__ h, const float* __restrict__ x,
                       const float* __restrict__ Wc1, const float* __restrict__ bc1,
                       const float* __restrict__ Wc2, const float* __restrict__ bc2,
                       const float* __restrict__ Wh1, const float* __restrict__ bh1,
                       const float* __restrict__ Wh2, const float* __restrict__ bh2,
                       float* __restrict__ out) {
    __shared__ float Wl[64*64];
    for (int t = threadIdx.x; t < 4096; t += blockDim.x) Wl[t] = Wc1[t];
    __syncthreads();
    int i = (blockIdx.x * blockDim.x + threadIdx.x) >> 6;
    int j = threadIdx.x & 63;
    if (i >= N_NODES) return;
    float acc = bc1[j];
    #pragma unroll 8
    for (int k = 0; k < 64; k++)
        acc += h[i*64+k] * Wl[k*64+j];
    acc = fmaxf(acc, 0.f);
    float p0 = wave_reduce_sum(acc * Wc2[j*4+0]);
    float p1 = wave_reduce_sum(acc * Wc2[j*4+1]);
    float p2 = wave_reduce_sum(acc * Wc2[j*4+2]);
    float p3 = wave_reduce_sum(acc * Wc2[j*4+3]);
    if (j == 0) {
        float f0 = x[i*8+6], f1 = x[i*8+7];
        float t8[8];
        #pragma unroll
        for (int q = 0; q < 8; q++)
            t8[q] = fmaxf(f0*Wh1[q] + f1*Wh1[8+q] + bh1[q], 0.f);
        float fl[4];
        #pragma unroll
        for (int q = 0; q < 4; q++) {
            float a = bh2[q];
            #pragma unroll
            for (int r = 0; r < 8; r++) a += t8[r]*Wh2[r*4+q];
            fl[q] = a;
        }
        out[i*4+0] = p0 + bc2[0] + 0.03f*fl[0];
        out[i*4+1] = p1 + bc2[1] + 0.03f*fl[1];
        out[i*4+2] = p2 + bc2[2] + 0.03f*fl[2];
        out[i*4+3] = p3 + bc2[3] + 0.03f*fl[3];
    }
}

extern "C" void kernel_launch(void* const* d_in, const int* in_sizes, int n_in,
                              void* d_out, int out_size, void* d_ws, size_t ws_size,
                              hipStream_t stream) {
    const float* x       = (const float*)d_in[0];
    const int*   ei      = (const int*)  d_in[1];
    const int*   batch   = (const int*)  d_in[2];
    const float* climber = (const float*)d_in[3];
    const float* W_in    = (const float*)d_in[4];
    const float* b_in    = (const float*)d_in[5];
    const float* ln_g    = (const float*)d_in[6];
    const float* ln_b    = (const float*)d_in[7];
    const float* W_c     = (const float*)d_in[8];
    const float* b_c     = (const float*)d_in[9];
    const float* Wf1     = (const float*)d_in[10];
    const float* bf1     = (const float*)d_in[11];
    const float* Wf2     = (const float*)d_in[12];
    const float* bf2     = (const float*)d_in[13];
    const float* Wg1     = (const float*)d_in[14];
    const float* as1     = (const float*)d_in[15];
    const float* ad1     = (const float*)d_in[16];
    const float* bg1     = (const float*)d_in[17];
    const float* Wg2     = (const float*)d_in[18];
    const float* as2     = (const float*)d_in[19];
    const float* ad2     = (const float*)d_in[20];
    const float* bg2     = (const float*)d_in[21];
    const float* Wc1     = (const float*)d_in[22];
    const float* bc1     = (const float*)d_in[23];
    const float* Wc2     = (const float*)d_in[24];
    const float* bc2     = (const float*)d_in[25];
    const float* Wh1     = (const float*)d_in[26];
    const float* bh1     = (const float*)d_in[27];
    const float* Wh2     = (const float*)d_in[28];
    const float* bh2     = (const float*)d_in[29];
    float* out = (float*)d_out;
    float* ws  = (float*)d_ws;

    // workspace carve: ~15M elements = 60 MB
    float* c       = ws;                   // 64,000
    float* gb1     = c   + 64000;          // 128,000
    float* gb2     = gb1 + 128000;         // 128,000
    float* h       = gb2 + 128000;         // 6,400,000
    float* z       = h   + 6400000;        // 6,400,000
    float* es      = z   + 6400000;        // 100,000
    float* ed      = es  + N_NODES;        // 100,000
    int*   deg     = (int*)(ed + N_NODES); // 100,000
    int*   cnt     = deg + N_NODES;        // 100,000
    int*   rowptr  = cnt + N_NODES;        // 100,001
    int*   csr_src = rowptr + N_NODES + 1; // 1,200,000

    // CSR build (topology is layer-invariant)
    hipMemsetAsync(deg, 0, N_NODES*sizeof(int), stream);
    hipMemsetAsync(cnt, 0, N_NODES*sizeof(int), stream);
    int edgeBlocks = (N_EDGES + 255)/256;
    k_deg    <<<edgeBlocks, 256, 0, stream>>>(ei, deg);
    k_scan   <<<1, 1024, 0, stream>>>(deg, rowptr);
    k_scatter<<<edgeBlocks, 256, 0, stream>>>(ei, rowptr, cnt, csr_src);

    // prologue
    k_climber<<<N_GRAPHS, 64, 0, stream>>>(climber, ln_g, ln_b, W_c, b_c, c);
    dim3 gB(N_GRAPHS, 2);
    k_film_coef<<<gB, 128, 0, stream>>>(c, Wf1, bf1, Wf2, bf2, gb1, gb2);

    int nodeBlocks = (N_NODES*64 + 255)/256;   // 1 node per wave, 4 waves/block
    k_node_init<<<nodeBlocks, 256, 0, stream>>>(x, batch, W_in, b_in, gb1, h);

    for (int layer = 0; layer < 2; layer++) {
        const float* Wg  = layer ? Wg2 : Wg1;
        const float* as_ = layer ? as2 : as1;
        const float* ad_ = layer ? ad2 : ad1;
        const float* bg  = layer ? bg2 : bg1;
        k_gat_z  <<<nodeBlocks, 256, 0, stream>>>(h, Wg, as_, ad_, z, es, ed);
        k_gat_agg<<<nodeBlocks, 256, 0, stream>>>(rowptr, csr_src, es, ed, z, bg,
                                                  batch, gb2, layer == 0 ? 1 : 0, h);
    }
    k_head<<<nodeBlocks, 256, 0, stream>>>(h, x, Wc1, bc1, Wc2, bc2,
                                           Wh1, bh1, Wh2, bh2, out);
}

// Round 3
// 809.348 us; speedup vs baseline: 1.5545x; 1.2301x over previous
//
#include <hip/hip_runtime.h>
#include <math.h>

#define N_NODES 100000
#define N_EDGES 1200000
#define N_GRAPHS 1000
#define HID 64
#define SCAN_B 256
#define N_PART ((N_NODES + SCAN_B - 1) / SCAN_B)   // 391

__device__ __forceinline__ float wave_reduce_sum(float v) {
    #pragma unroll
    for (int off = 32; off > 0; off >>= 1)
        v += __shfl_xor(v, off, 64);
    return v;
}

// ---------------- CSR build (once per call, reused by both layers) -----------

__global__ void k_deg(const int* __restrict__ ei, int* __restrict__ deg) {
    int e = blockIdx.x * blockDim.x + threadIdx.x;
    if (e >= N_EDGES) return;
    atomicAdd(&deg[ei[N_EDGES + e]], 1);
}

// stage A: per-block partial sums of deg
__global__ void k_scan_partial(const int* __restrict__ deg, int* __restrict__ part) {
    int i = blockIdx.x * SCAN_B + threadIdx.x;
    int v = (i < N_NODES) ? deg[i] : 0;
    __shared__ int red[SCAN_B / 64];
    int w = wave_reduce_sum((float)v);   // int fits exactly in float? deg<=~50, sum<=256*50 ok
    // safer: integer shuffle reduce
    int iv = v;
    #pragma unroll
    for (int off = 32; off > 0; off >>= 1)
        iv += __shfl_xor(iv, off, 64);
    (void)w;
    if ((threadIdx.x & 63) == 0) red[threadIdx.x >> 6] = iv;
    __syncthreads();
    if (threadIdx.x == 0) {
        int s = 0;
        #pragma unroll
        for (int k = 0; k < SCAN_B / 64; k++) s += red[k];
        part[blockIdx.x] = s;
    }
}

// stage B: single small block scans the partials (exclusive), writes total
__global__ void k_scan_part2(int* __restrict__ part, int* __restrict__ rowptr) {
    __shared__ int sh[512];
    int t = threadIdx.x;
    int v = (t < N_PART) ? part[t] : 0;
    sh[t] = v;
    __syncthreads();
    for (int off = 1; off < 512; off <<= 1) {
        int u = (t >= off) ? sh[t - off] : 0;
        __syncthreads();
        sh[t] += u;
        __syncthreads();
    }
    if (t < N_PART) part[t] = sh[t] - v;           // exclusive
    if (t == 511) rowptr[N_NODES] = sh[511];       // total
}

// stage C: in-block exclusive scan + block offset -> rowptr
__global__ void k_scan_final(const int* __restrict__ deg, const int* __restrict__ part,
                             int* __restrict__ rowptr) {
    __shared__ int sh[SCAN_B];
    int t = threadIdx.x;
    int i = blockIdx.x * SCAN_B + t;
    int v = (i < N_NODES) ? deg[i] : 0;
    sh[t] = v;
    __syncthreads();
    for (int off = 1; off < SCAN_B; off <<= 1) {
        int u = (t >= off) ? sh[t - off] : 0;
        __syncthreads();
        sh[t] += u;
        __syncthreads();
    }
    if (i < N_NODES) rowptr[i] = part[blockIdx.x] + sh[t] - v;
}

__global__ void k_scatter(const int* __restrict__ ei, const int* __restrict__ rowptr,
                          int* __restrict__ cnt, int* __restrict__ csr_src) {
    int e = blockIdx.x * blockDim.x + threadIdx.x;
    if (e >= N_EDGES) return;
    int src = ei[e], dst = ei[N_EDGES + e];
    int pos = atomicAdd(&cnt[dst], 1);
    csr_src[rowptr[dst] + pos] = src;
}

// ---------------- small dense prologue --------------------------------------

__global__ void k_climber(const float* __restrict__ climber,
                          const float* __restrict__ ln_g, const float* __restrict__ ln_b,
                          const float* __restrict__ W_c, const float* __restrict__ b_c,
                          float* __restrict__ c) {
    int g = blockIdx.x;
    int j = threadIdx.x;
    float v[6];
    float mu = 0.f;
    #pragma unroll
    for (int k = 0; k < 6; k++) { v[k] = climber[g*6+k]; mu += v[k]; }
    mu *= (1.f/6.f);
    float var = 0.f;
    #pragma unroll
    for (int k = 0; k < 6; k++) { float d = v[k]-mu; var += d*d; }
    var *= (1.f/6.f);
    float rs = rsqrtf(var + 1e-5f);
    float acc = b_c[j];
    #pragma unroll
    for (int k = 0; k < 6; k++) {
        float cn = (v[k]-mu)*rs*ln_g[k] + ln_b[k];
        acc += cn * W_c[k*64+j];
    }
    c[g*64+j] = fmaxf(acc, 0.f);
}

__global__ void k_film_coef(const float* __restrict__ c,
                            const float* __restrict__ Wf1, const float* __restrict__ bf1,
                            const float* __restrict__ Wf2, const float* __restrict__ bf2,
                            float* __restrict__ gb1, float* __restrict__ gb2) {
    int g = blockIdx.x;
    const float* Wf = blockIdx.y ? Wf2 : Wf1;
    const float* bf = blockIdx.y ? bf2 : bf1;
    float*       gb = blockIdx.y ? gb2 : gb1;
    int j = threadIdx.x;
    float acc = bf[j];
    #pragma unroll 8
    for (int k = 0; k < 64; k++)
        acc += c[g*64+k] * Wf[k*128+j];
    gb[g*128+j] = acc;
}

__global__ void k_node_init(const float* __restrict__ x, const int* __restrict__ batch,
                            const float* __restrict__ W_in, const float* __restrict__ b_in,
                            const float* __restrict__ gb1, float* __restrict__ h) {
    int i = (blockIdx.x * blockDim.x + threadIdx.x) >> 6;
    int j = threadIdx.x & 63;
    if (i >= N_NODES) return;
    float acc = b_in[j];
    #pragma unroll
    for (int k = 0; k < 6; k++)
        acc += x[i*8+k] * W_in[k*64+j];
    int g = batch[i];
    h[i*64+j] = acc * (1.f + gb1[g*128+j]) + gb1[g*128+64+j];
}

// ---------------- GAT layer -------------------------------------------------

// z = h @ Wg ; es = z@a_src ; ed = z@a_dst   one wave per node, Wg in LDS
__global__ void k_gat_z(const float* __restrict__ h, const float* __restrict__ Wg,
                        const float* __restrict__ a_src, const float* __restrict__ a_dst,
                        float* __restrict__ z, float* __restrict__ es, float* __restrict__ ed) {
    __shared__ float Wl[64*64];
    for (int t = threadIdx.x; t < 4096; t += blockDim.x) Wl[t] = Wg[t];
    __syncthreads();
    int i = (blockIdx.x * blockDim.x + threadIdx.x) >> 6;
    int j = threadIdx.x & 63;
    if (i >= N_NODES) return;
    float acc = 0.f;
    #pragma unroll 8
    for (int k = 0; k < 64; k++)
        acc += h[i*64+k] * Wl[k*64+j];
    z[i*64+j] = acc;
    float ps = wave_reduce_sum(acc * a_src[j]);
    float pd = wave_reduce_sum(acc * a_dst[j]);
    if (j == 0) { es[i] = ps; ed[i] = pd; }
}

// Fused softmax + aggregation + relu + bias (+FiLM), one wave per dst node.
__global__ void k_gat_agg(const int* __restrict__ rowptr, const int* __restrict__ csr_src,
                          const float* __restrict__ es, const float* __restrict__ ed,
                          const float* __restrict__ z, const float* __restrict__ bg,
                          const int* __restrict__ batch, const float* __restrict__ gb,
                          int apply_film, float* __restrict__ h) {
    int i = (blockIdx.x * blockDim.x + threadIdx.x) >> 6;
    int j = threadIdx.x & 63;
    if (i >= N_NODES) return;
    int beg = rowptr[i], end = rowptr[i+1];
    float edi = ed[i];

    float e_self = es[i] + edi;
    e_self = (e_self > 0.f) ? e_self : 0.2f * e_self;

    // pass A: segment max, lane-parallel
    float m = e_self;
    for (int k = beg + j; k < end; k += 64) {
        float v = es[csr_src[k]] + edi;
        v = (v > 0.f) ? v : 0.2f * v;
        m = fmaxf(m, v);
    }
    #pragma unroll
    for (int off = 32; off > 0; off >>= 1)
        m = fmaxf(m, __shfl_xor(m, off, 64));

    // pass B: serial over edges, feature-parallel accumulate
    float ex = expf(e_self - m);
    float s = ex;
    float acc = ex * z[i*64 + j];
    for (int k = beg; k < end; k++) {
        int src = csr_src[k];
        float v = es[src] + edi;
        v = (v > 0.f) ? v : 0.2f * v;
        float e2 = expf(v - m);
        s += e2;
        acc += e2 * z[src*64 + j];
    }
    float o = acc / (s + 1e-16f);
    o = fmaxf(o + bg[j], 0.f);
    if (apply_film) {
        int g = batch[i];
        o = o * (1.f + gb[g*128+j]) + gb[g*128+64+j];
    }
    h[i*64+j] = o;
}

// ---------------- head ------------------------------------------------------

__global__ void k_head(const float* __restrict__ h, const float* __restrict__ x,
                       const float* __restrict__ Wc1, const float* __restrict__ bc1,
                       const float* __restrict__ Wc2, const float* __restrict__ bc2,
                       const float* __restrict__ Wh1, const float* __restrict__ bh1,
                       const float* __restrict__ Wh2, const float* __restrict__ bh2,
                       float* __restrict__ out) {
    __shared__ float Wl[64*64];
    for (int t = threadIdx.x; t < 4096; t += blockDim.x) Wl[t] = Wc1[t];
    __syncthreads();
    int i = (blockIdx.x * blockDim.x + threadIdx.x) >> 6;
    int j = threadIdx.x & 63;
    if (i >= N_NODES) return;
    float acc = bc1[j];
    #pragma unroll 8
    for (int k = 0; k < 64; k++)
        acc += h[i*64+k] * Wl[k*64+j];
    acc = fmaxf(acc, 0.f);
    float p0 = wave_reduce_sum(acc * Wc2[j*4+0]);
    float p1 = wave_reduce_sum(acc * Wc2[j*4+1]);
    float p2 = wave_reduce_sum(acc * Wc2[j*4+2]);
    float p3 = wave_reduce_sum(acc * Wc2[j*4+3]);
    if (j == 0) {
        float f0 = x[i*8+6], f1 = x[i*8+7];
        float t8[8];
        #pragma unroll
        for (int q = 0; q < 8; q++)
            t8[q] = fmaxf(f0*Wh1[q] + f1*Wh1[8+q] + bh1[q], 0.f);
        float fl[4];
        #pragma unroll
        for (int q = 0; q < 4; q++) {
            float a = bh2[q];
            #pragma unroll
            for (int r = 0; r < 8; r++) a += t8[r]*Wh2[r*4+q];
            fl[q] = a;
        }
        out[i*4+0] = p0 + bc2[0] + 0.03f*fl[0];
        out[i*4+1] = p1 + bc2[1] + 0.03f*fl[1];
        out[i*4+2] = p2 + bc2[2] + 0.03f*fl[2];
        out[i*4+3] = p3 + bc2[3] + 0.03f*fl[3];
    }
}

extern "C" void kernel_launch(void* const* d_in, const int* in_sizes, int n_in,
                              void* d_out, int out_size, void* d_ws, size_t ws_size,
                              hipStream_t stream) {
    const float* x       = (const float*)d_in[0];
    const int*   ei      = (const int*)  d_in[1];
    const int*   batch   = (const int*)  d_in[2];
    const float* climber = (const float*)d_in[3];
    const float* W_in    = (const float*)d_in[4];
    const float* b_in    = (const float*)d_in[5];
    const float* ln_g    = (const float*)d_in[6];
    const float* ln_b    = (const float*)d_in[7];
    const float* W_c     = (const float*)d_in[8];
    const float* b_c     = (const float*)d_in[9];
    const float* Wf1     = (const float*)d_in[10];
    const float* bf1     = (const float*)d_in[11];
    const float* Wf2     = (const float*)d_in[12];
    const float* bf2     = (const float*)d_in[13];
    const float* Wg1     = (const float*)d_in[14];
    const float* as1     = (const float*)d_in[15];
    const float* ad1     = (const float*)d_in[16];
    const float* bg1     = (const float*)d_in[17];
    const float* Wg2     = (const float*)d_in[18];
    const float* as2     = (const float*)d_in[19];
    const float* ad2     = (const float*)d_in[20];
    const float* bg2     = (const float*)d_in[21];
    const float* Wc1     = (const float*)d_in[22];
    const float* bc1     = (const float*)d_in[23];
    const float* Wc2     = (const float*)d_in[24];
    const float* bc2     = (const float*)d_in[25];
    const float* Wh1     = (const float*)d_in[26];
    const float* bh1     = (const float*)d_in[27];
    const float* Wh2     = (const float*)d_in[28];
    const float* bh2     = (const float*)d_in[29];
    float* out = (float*)d_out;
    float* ws  = (float*)d_ws;

    // workspace carve
    float* c       = ws;                   // 64,000
    float* gb1     = c   + 64000;          // 128,000
    float* gb2     = gb1 + 128000;         // 128,000
    float* h       = gb2 + 128000;         // 6,400,000
    float* z       = h   + 6400000;        // 6,400,000
    float* es      = z   + 6400000;        // 100,000
    float* ed      = es  + N_NODES;        // 100,000
    int*   deg     = (int*)(ed + N_NODES); // 100,000
    int*   cnt     = deg + N_NODES;        // 100,000
    int*   rowptr  = cnt + N_NODES;        // 100,001
    int*   csr_src = rowptr + N_NODES + 1; // 1,200,000
    int*   part    = csr_src + N_EDGES;    // N_PART

    // CSR build (topology is layer-invariant)
    hipMemsetAsync(deg, 0, N_NODES*sizeof(int), stream);
    hipMemsetAsync(cnt, 0, N_NODES*sizeof(int), stream);
    int edgeBlocks = (N_EDGES + 255)/256;
    k_deg         <<<edgeBlocks, 256, 0, stream>>>(ei, deg);
    k_scan_partial<<<N_PART, SCAN_B, 0, stream>>>(deg, part);
    k_scan_part2  <<<1, 512, 0, stream>>>(part, rowptr);
    k_scan_final  <<<N_PART, SCAN_B, 0, stream>>>(deg, part, rowptr);
    k_scatter     <<<edgeBlocks, 256, 0, stream>>>(ei, rowptr, cnt, csr_src);

    // prologue
    k_climber<<<N_GRAPHS, 64, 0, stream>>>(climber, ln_g, ln_b, W_c, b_c, c);
    dim3 gB(N_GRAPHS, 2);
    k_film_coef<<<gB, 128, 0, stream>>>(c, Wf1, bf1, Wf2, bf2, gb1, gb2);

    int nodeBlocks = (N_NODES*64 + 255)/256;   // 1 node per wave, 4 waves/block
    k_node_init<<<nodeBlocks, 256, 0, stream>>>(x, batch, W_in, b_in, gb1, h);

    for (int layer = 0; layer < 2; layer++) {
        const float* Wg  = layer ? Wg2 : Wg1;
        const float* as_ = layer ? as2 : as1;
        const float* ad_ = layer ? ad2 : ad1;
        const float* bg  = layer ? bg2 : bg1;
        k_gat_z  <<<nodeBlocks, 256, 0, stream>>>(h, Wg, as_, ad_, z, es, ed);
        k_gat_agg<<<nodeBlocks, 256, 0, stream>>>(rowptr, csr_src, es, ed, z, bg,
                                                  batch, gb2, layer == 0 ? 1 : 0, h);
    }
    k_head<<<nodeBlocks, 256, 0, stream>>>(h, x, Wc1, bc1, Wc2, bc2,
                                           Wh1, bh1, Wh2, bh2, out);
}

// Round 4
// 497.908 us; speedup vs baseline: 2.5268x; 1.6255x over previous
//
#include <hip/hip_runtime.h>
#include <math.h>

#define N_NODES 100000
#define N_EDGES 1200000
#define N_GRAPHS 1000
#define HID 64
#define SCAN_B 256
#define N_PART ((N_NODES + SCAN_B - 1) / SCAN_B)   // 391

// ---------------- CSR build (once per call, reused by both layers) -----------

__global__ void k_deg(const int* __restrict__ ei, int* __restrict__ deg) {
    int e = blockIdx.x * blockDim.x + threadIdx.x;
    if (e >= N_EDGES) return;
    atomicAdd(&deg[ei[N_EDGES + e]], 1);
}

__global__ void k_scan_partial(const int* __restrict__ deg, int* __restrict__ part) {
    int i = blockIdx.x * SCAN_B + threadIdx.x;
    int v = (i < N_NODES) ? deg[i] : 0;
    __shared__ int red[SCAN_B / 64];
    int iv = v;
    #pragma unroll
    for (int off = 32; off > 0; off >>= 1)
        iv += __shfl_xor(iv, off, 64);
    if ((threadIdx.x & 63) == 0) red[threadIdx.x >> 6] = iv;
    __syncthreads();
    if (threadIdx.x == 0) {
        int s = 0;
        #pragma unroll
        for (int k = 0; k < SCAN_B / 64; k++) s += red[k];
        part[blockIdx.x] = s;
    }
}

__global__ void k_scan_part2(int* __restrict__ part, int* __restrict__ rowptr) {
    __shared__ int sh[512];
    int t = threadIdx.x;
    int v = (t < N_PART) ? part[t] : 0;
    sh[t] = v;
    __syncthreads();
    for (int off = 1; off < 512; off <<= 1) {
        int u = (t >= off) ? sh[t - off] : 0;
        __syncthreads();
        sh[t] += u;
        __syncthreads();
    }
    if (t < N_PART) part[t] = sh[t] - v;           // exclusive
    if (t == 511) rowptr[N_NODES] = sh[511];       // total
}

__global__ void k_scan_final(const int* __restrict__ deg, const int* __restrict__ part,
                             int* __restrict__ rowptr) {
    __shared__ int sh[SCAN_B];
    int t = threadIdx.x;
    int i = blockIdx.x * SCAN_B + t;
    int v = (i < N_NODES) ? deg[i] : 0;
    sh[t] = v;
    __syncthreads();
    for (int off = 1; off < SCAN_B; off <<= 1) {
        int u = (t >= off) ? sh[t - off] : 0;
        __syncthreads();
        sh[t] += u;
        __syncthreads();
    }
    if (i < N_NODES) rowptr[i] = part[blockIdx.x] + sh[t] - v;
}

__global__ void k_scatter(const int* __restrict__ ei, const int* __restrict__ rowptr,
                          int* __restrict__ cnt, int* __restrict__ csr_src) {
    int e = blockIdx.x * blockDim.x + threadIdx.x;
    if (e >= N_EDGES) return;
    int src = ei[e], dst = ei[N_EDGES + e];
    int pos = atomicAdd(&cnt[dst], 1);
    csr_src[rowptr[dst] + pos] = src;
}

// ---------------- small dense prologue --------------------------------------

__global__ void k_climber(const float* __restrict__ climber,
                          const float* __restrict__ ln_g, const float* __restrict__ ln_b,
                          const float* __restrict__ W_c, const float* __restrict__ b_c,
                          float* __restrict__ c) {
    int g = blockIdx.x;
    int j = threadIdx.x;
    float v[6];
    float mu = 0.f;
    #pragma unroll
    for (int k = 0; k < 6; k++) { v[k] = climber[g*6+k]; mu += v[k]; }
    mu *= (1.f/6.f);
    float var = 0.f;
    #pragma unroll
    for (int k = 0; k < 6; k++) { float d = v[k]-mu; var += d*d; }
    var *= (1.f/6.f);
    float rs = rsqrtf(var + 1e-5f);
    float acc = b_c[j];
    #pragma unroll
    for (int k = 0; k < 6; k++) {
        float cn = (v[k]-mu)*rs*ln_g[k] + ln_b[k];
        acc += cn * W_c[k*64+j];
    }
    c[g*64+j] = fmaxf(acc, 0.f);
}

__global__ void k_film_coef(const float* __restrict__ c,
                            const float* __restrict__ Wf1, const float* __restrict__ bf1,
                            const float* __restrict__ Wf2, const float* __restrict__ bf2,
                            float* __restrict__ gb1, float* __restrict__ gb2) {
    int g = blockIdx.x;
    const float* Wf = blockIdx.y ? Wf2 : Wf1;
    const float* bf = blockIdx.y ? bf2 : bf1;
    float*       gb = blockIdx.y ? gb2 : gb1;
    int j = threadIdx.x;
    float acc = bf[j];
    #pragma unroll 8
    for (int k = 0; k < 64; k++)
        acc += c[g*64+k] * Wf[k*128+j];
    gb[g*128+j] = acc;
}

// 4 nodes per wave, 16 lanes/node, float4 per lane
__global__ void k_node_init(const float* __restrict__ x, const int* __restrict__ batch,
                            const float* __restrict__ W_in, const float* __restrict__ b_in,
                            const float* __restrict__ gb1, float* __restrict__ h) {
    int tid = blockIdx.x * blockDim.x + threadIdx.x;
    int i  = tid >> 4;
    int sl = threadIdx.x & 15;
    if (i >= N_NODES) return;
    const float4* W4 = (const float4*)W_in;
    float4 acc = ((const float4*)b_in)[sl];
    #pragma unroll
    for (int k = 0; k < 6; k++) {
        float xk = x[i*8+k];
        float4 w = W4[k*16 + sl];
        acc.x += xk*w.x; acc.y += xk*w.y; acc.z += xk*w.z; acc.w += xk*w.w;
    }
    int g = batch[i];
    const float4* gb4 = (const float4*)gb1;
    float4 ga = gb4[g*32 + sl];
    float4 be = gb4[g*32 + 16 + sl];
    acc.x = acc.x*(1.f+ga.x) + be.x;
    acc.y = acc.y*(1.f+ga.y) + be.y;
    acc.z = acc.z*(1.f+ga.z) + be.z;
    acc.w = acc.w*(1.f+ga.w) + be.w;
    ((float4*)h)[i*16 + sl] = acc;
}

// ---------------- GAT layer -------------------------------------------------

// z = h @ Wg ; es = z@a_src ; ed = z@a_dst
// 4 nodes/wave: lane = (node group, sub-lane sl), lane sl holds cols 4sl..4sl+3
__global__ void k_gat_z(const float* __restrict__ h, const float* __restrict__ Wg,
                        const float* __restrict__ a_src, const float* __restrict__ a_dst,
                        float* __restrict__ z, float* __restrict__ es, float* __restrict__ ed) {
    __shared__ float4 Wl[64*16];                 // W[k][4c..4c+3]
    const float4* Wg4 = (const float4*)Wg;
    for (int t = threadIdx.x; t < 1024; t += blockDim.x) Wl[t] = Wg4[t];
    __syncthreads();
    int tid = blockIdx.x * blockDim.x + threadIdx.x;
    int i  = tid >> 4;
    int sl = threadIdx.x & 15;
    if (i >= N_NODES) return;
    float4 hr = ((const float4*)h)[i*16 + sl];
    float hv[4] = {hr.x, hr.y, hr.z, hr.w};
    float4 acc = {0.f, 0.f, 0.f, 0.f};
    #pragma unroll
    for (int k = 0; k < 64; k++) {
        float hk = __shfl(hv[k & 3], k >> 2, 16);   // broadcast h[i][k] within group
        float4 w = Wl[k*16 + sl];
        acc.x += hk*w.x; acc.y += hk*w.y; acc.z += hk*w.z; acc.w += hk*w.w;
    }
    ((float4*)z)[i*16 + sl] = acc;
    float4 as4 = ((const float4*)a_src)[sl];
    float4 ad4 = ((const float4*)a_dst)[sl];
    float ps = acc.x*as4.x + acc.y*as4.y + acc.z*as4.z + acc.w*as4.w;
    float pd = acc.x*ad4.x + acc.y*ad4.y + acc.z*ad4.z + acc.w*ad4.w;
    #pragma unroll
    for (int off = 1; off < 16; off <<= 1) {
        ps += __shfl_xor(ps, off, 16);
        pd += __shfl_xor(pd, off, 16);
    }
    if (sl == 0) { es[i] = ps; ed[i] = pd; }
}

// Fused softmax + aggregation + relu + bias (+FiLM), 4 dst nodes per wave.
__global__ void k_gat_agg(const int* __restrict__ rowptr, const int* __restrict__ csr_src,
                          const float* __restrict__ es, const float* __restrict__ ed,
                          const float* __restrict__ z, const float* __restrict__ bg,
                          const int* __restrict__ batch, const float* __restrict__ gb,
                          int apply_film, float* __restrict__ h) {
    int tid = blockIdx.x * blockDim.x + threadIdx.x;
    int i  = tid >> 4;
    int sl = threadIdx.x & 15;
    if (i >= N_NODES) return;
    int beg = rowptr[i], end = rowptr[i+1];
    float edi = ed[i];

    float e_self = es[i] + edi;
    e_self = fmaxf(e_self, 0.2f * e_self);        // leaky_relu(0.2)

    // pass A: segment max, 16-lane-parallel
    float m = e_self;
    for (int k = beg + sl; k < end; k += 16) {
        float v = es[csr_src[k]] + edi;
        v = fmaxf(v, 0.2f * v);
        m = fmaxf(m, v);
    }
    #pragma unroll
    for (int off = 1; off < 16; off <<= 1)
        m = fmaxf(m, __shfl_xor(m, off, 16));

    // pass B: serial over edges (per group), feature-parallel float4 accumulate
    float ex = __expf(e_self - m);
    float s = ex;
    float4 zi = ((const float4*)z)[i*16 + sl];
    float4 acc;
    acc.x = ex*zi.x; acc.y = ex*zi.y; acc.z = ex*zi.z; acc.w = ex*zi.w;
    for (int k = beg; k < end; k++) {
        int src = csr_src[k];
        float v = es[src] + edi;
        v = fmaxf(v, 0.2f * v);
        float e2 = __expf(v - m);
        s += e2;
        float4 zr = ((const float4*)z)[src*16 + sl];
        acc.x += e2*zr.x; acc.y += e2*zr.y; acc.z += e2*zr.z; acc.w += e2*zr.w;
    }
    float inv = 1.f / (s + 1e-16f);
    float4 bg4 = ((const float4*)bg)[sl];
    float4 o;
    o.x = fmaxf(acc.x*inv + bg4.x, 0.f);
    o.y = fmaxf(acc.y*inv + bg4.y, 0.f);
    o.z = fmaxf(acc.z*inv + bg4.z, 0.f);
    o.w = fmaxf(acc.w*inv + bg4.w, 0.f);
    if (apply_film) {
        int g = batch[i];
        const float4* gb4 = (const float4*)gb;
        float4 ga = gb4[g*32 + sl];
        float4 be = gb4[g*32 + 16 + sl];
        o.x = o.x*(1.f+ga.x) + be.x;
        o.y = o.y*(1.f+ga.y) + be.y;
        o.z = o.z*(1.f+ga.z) + be.z;
        o.w = o.w*(1.f+ga.w) + be.w;
    }
    ((float4*)h)[i*16 + sl] = o;
}

// ---------------- head ------------------------------------------------------

__global__ void k_head(const float* __restrict__ h, const float* __restrict__ x,
                       const float* __restrict__ Wc1, const float* __restrict__ bc1,
                       const float* __restrict__ Wc2, const float* __restrict__ bc2,
                       const float* __restrict__ Wh1, const float* __restrict__ bh1,
                       const float* __restrict__ Wh2, const float* __restrict__ bh2,
                       float* __restrict__ out) {
    __shared__ float4 Wl[64*16];
    const float4* Wc14 = (const float4*)Wc1;
    for (int t = threadIdx.x; t < 1024; t += blockDim.x) Wl[t] = Wc14[t];
    __syncthreads();
    int tid = blockIdx.x * blockDim.x + threadIdx.x;
    int i  = tid >> 4;
    int sl = threadIdx.x & 15;
    if (i >= N_NODES) return;
    float4 hr = ((const float4*)h)[i*16 + sl];
    float hv[4] = {hr.x, hr.y, hr.z, hr.w};
    float4 acc = ((const float4*)bc1)[sl];
    #pragma unroll
    for (int k = 0; k < 64; k++) {
        float hk = __shfl(hv[k & 3], k >> 2, 16);
        float4 w = Wl[k*16 + sl];
        acc.x += hk*w.x; acc.y += hk*w.y; acc.z += hk*w.z; acc.w += hk*w.w;
    }
    acc.x = fmaxf(acc.x, 0.f); acc.y = fmaxf(acc.y, 0.f);
    acc.z = fmaxf(acc.z, 0.f); acc.w = fmaxf(acc.w, 0.f);
    // project 64 -> 4: p[q] = sum_j acc_j * Wc2[j][q]
    const float4* Wc24 = (const float4*)Wc2;      // row j = Wc2[j][0..3]
    float4 r0 = Wc24[sl*4+0], r1 = Wc24[sl*4+1], r2 = Wc24[sl*4+2], r3 = Wc24[sl*4+3];
    float4 p;
    p.x = acc.x*r0.x + acc.y*r1.x + acc.z*r2.x + acc.w*r3.x;
    p.y = acc.x*r0.y + acc.y*r1.y + acc.z*r2.y + acc.w*r3.y;
    p.z = acc.x*r0.z + acc.y*r1.z + acc.z*r2.z + acc.w*r3.z;
    p.w = acc.x*r0.w + acc.y*r1.w + acc.z*r2.w + acc.w*r3.w;
    #pragma unroll
    for (int off = 1; off < 16; off <<= 1) {
        p.x += __shfl_xor(p.x, off, 16);
        p.y += __shfl_xor(p.y, off, 16);
        p.z += __shfl_xor(p.z, off, 16);
        p.w += __shfl_xor(p.w, off, 16);
    }
    if (sl == 0) {
        float f0 = x[i*8+6], f1 = x[i*8+7];
        float t8[8];
        #pragma unroll
        for (int q = 0; q < 8; q++)
            t8[q] = fmaxf(f0*Wh1[q] + f1*Wh1[8+q] + bh1[q], 0.f);
        float4 o;
        float fl[4];
        #pragma unroll
        for (int q = 0; q < 4; q++) {
            float a = bh2[q];
            #pragma unroll
            for (int r = 0; r < 8; r++) a += t8[r]*Wh2[r*4+q];
            fl[q] = a;
        }
        o.x = p.x + bc2[0] + 0.03f*fl[0];
        o.y = p.y + bc2[1] + 0.03f*fl[1];
        o.z = p.z + bc2[2] + 0.03f*fl[2];
        o.w = p.w + bc2[3] + 0.03f*fl[3];
        ((float4*)out)[i] = o;
    }
}

extern "C" void kernel_launch(void* const* d_in, const int* in_sizes, int n_in,
                              void* d_out, int out_size, void* d_ws, size_t ws_size,
                              hipStream_t stream) {
    const float* x       = (const float*)d_in[0];
    const int*   ei      = (const int*)  d_in[1];
    const int*   batch   = (const int*)  d_in[2];
    const float* climber = (const float*)d_in[3];
    const float* W_in    = (const float*)d_in[4];
    const float* b_in    = (const float*)d_in[5];
    const float* ln_g    = (const float*)d_in[6];
    const float* ln_b    = (const float*)d_in[7];
    const float* W_c     = (const float*)d_in[8];
    const float* b_c     = (const float*)d_in[9];
    const float* Wf1     = (const float*)d_in[10];
    const float* bf1     = (const float*)d_in[11];
    const float* Wf2     = (const float*)d_in[12];
    const float* bf2     = (const float*)d_in[13];
    const float* Wg1     = (const float*)d_in[14];
    const float* as1     = (const float*)d_in[15];
    const float* ad1     = (const float*)d_in[16];
    const float* bg1     = (const float*)d_in[17];
    const float* Wg2     = (const float*)d_in[18];
    const float* as2     = (const float*)d_in[19];
    const float* ad2     = (const float*)d_in[20];
    const float* bg2     = (const float*)d_in[21];
    const float* Wc1     = (const float*)d_in[22];
    const float* bc1     = (const float*)d_in[23];
    const float* Wc2     = (const float*)d_in[24];
    const float* bc2     = (const float*)d_in[25];
    const float* Wh1     = (const float*)d_in[26];
    const float* bh1     = (const float*)d_in[27];
    const float* Wh2     = (const float*)d_in[28];
    const float* bh2     = (const float*)d_in[29];
    float* out = (float*)d_out;
    float* ws  = (float*)d_ws;

    // workspace carve
    float* c       = ws;                   // 64,000
    float* gb1     = c   + 64000;          // 128,000
    float* gb2     = gb1 + 128000;         // 128,000
    float* h       = gb2 + 128000;         // 6,400,000
    float* z       = h   + 6400000;        // 6,400,000
    float* es      = z   + 6400000;        // 100,000
    float* ed      = es  + N_NODES;        // 100,000
    int*   deg     = (int*)(ed + N_NODES); // 100,000
    int*   cnt     = deg + N_NODES;        // 100,000
    int*   rowptr  = cnt + N_NODES;        // 100,001
    int*   csr_src = rowptr + N_NODES + 1; // 1,200,000
    int*   part    = csr_src + N_EDGES;    // N_PART

    // CSR build (topology is layer-invariant)
    hipMemsetAsync(deg, 0, N_NODES*sizeof(int), stream);
    hipMemsetAsync(cnt, 0, N_NODES*sizeof(int), stream);
    int edgeBlocks = (N_EDGES + 255)/256;
    k_deg         <<<edgeBlocks, 256, 0, stream>>>(ei, deg);
    k_scan_partial<<<N_PART, SCAN_B, 0, stream>>>(deg, part);
    k_scan_part2  <<<1, 512, 0, stream>>>(part, rowptr);
    k_scan_final  <<<N_PART, SCAN_B, 0, stream>>>(deg, part, rowptr);
    k_scatter     <<<edgeBlocks, 256, 0, stream>>>(ei, rowptr, cnt, csr_src);

    // prologue
    k_climber<<<N_GRAPHS, 64, 0, stream>>>(climber, ln_g, ln_b, W_c, b_c, c);
    dim3 gB(N_GRAPHS, 2);
    k_film_coef<<<gB, 128, 0, stream>>>(c, Wf1, bf1, Wf2, bf2, gb1, gb2);

    int nodeBlocks = (N_NODES*16 + 255)/256;   // 6250: 4 nodes/wave, 16 nodes/block
    k_node_init<<<nodeBlocks, 256, 0, stream>>>(x, batch, W_in, b_in, gb1, h);

    for (int layer = 0; layer < 2; layer++) {
        const float* Wg  = layer ? Wg2 : Wg1;
        const float* as_ = layer ? as2 : as1;
        const float* ad_ = layer ? ad2 : ad1;
        const float* bg  = layer ? bg2 : bg1;
        k_gat_z  <<<nodeBlocks, 256, 0, stream>>>(h, Wg, as_, ad_, z, es, ed);
        k_gat_agg<<<nodeBlocks, 256, 0, stream>>>(rowptr, csr_src, es, ed, z, bg,
                                                  batch, gb2, layer == 0 ? 1 : 0, h);
    }
    k_head<<<nodeBlocks, 256, 0, stream>>>(h, x, Wc1, bc1, Wc2, bc2,
                                           Wh1, bh1, Wh2, bh2, out);
}

// Round 5
// 460.095 us; speedup vs baseline: 2.7345x; 1.0822x over previous
//
#include <hip/hip_runtime.h>
#include <math.h>

#define N_NODES 100000
#define N_EDGES 1200000
#define N_GRAPHS 1000
#define HID 64
#define SCAN_B 256
#define N_PART ((N_NODES + SCAN_B - 1) / SCAN_B)   // 391

// ---------------- CSR build (once per call, reused by both layers) -----------

__global__ void k_deg(const int* __restrict__ ei, int* __restrict__ deg) {
    int e = blockIdx.x * blockDim.x + threadIdx.x;
    if (e >= N_EDGES) return;
    atomicAdd(&deg[ei[N_EDGES + e]], 1);
}

__global__ void k_scan_partial(const int* __restrict__ deg, int* __restrict__ part) {
    int i = blockIdx.x * SCAN_B + threadIdx.x;
    int v = (i < N_NODES) ? deg[i] : 0;
    __shared__ int red[SCAN_B / 64];
    int iv = v;
    #pragma unroll
    for (int off = 32; off > 0; off >>= 1)
        iv += __shfl_xor(iv, off, 64);
    if ((threadIdx.x & 63) == 0) red[threadIdx.x >> 6] = iv;
    __syncthreads();
    if (threadIdx.x == 0) {
        int s = 0;
        #pragma unroll
        for (int k = 0; k < SCAN_B / 64; k++) s += red[k];
        part[blockIdx.x] = s;
    }
}

__global__ void k_scan_part2(int* __restrict__ part, int* __restrict__ rowptr) {
    __shared__ int sh[512];
    int t = threadIdx.x;
    int v = (t < N_PART) ? part[t] : 0;
    sh[t] = v;
    __syncthreads();
    for (int off = 1; off < 512; off <<= 1) {
        int u = (t >= off) ? sh[t - off] : 0;
        __syncthreads();
        sh[t] += u;
        __syncthreads();
    }
    if (t < N_PART) part[t] = sh[t] - v;           // exclusive
    if (t == 511) rowptr[N_NODES] = sh[511];       // total
}

__global__ void k_scan_final(const int* __restrict__ deg, const int* __restrict__ part,
                             int* __restrict__ rowptr) {
    __shared__ int sh[SCAN_B];
    int t = threadIdx.x;
    int i = blockIdx.x * SCAN_B + t;
    int v = (i < N_NODES) ? deg[i] : 0;
    sh[t] = v;
    __syncthreads();
    for (int off = 1; off < SCAN_B; off <<= 1) {
        int u = (t >= off) ? sh[t - off] : 0;
        __syncthreads();
        sh[t] += u;
        __syncthreads();
    }
    if (i < N_NODES) rowptr[i] = part[blockIdx.x] + sh[t] - v;
}

// store via fire-and-forget atomicExch: executes at fabric/MALL, avoids the
// partial-dirty-line L2 writeback amplification (87 MB for 4.8 MB of data).
__global__ void k_scatter(const int* __restrict__ ei, const int* __restrict__ rowptr,
                          int* __restrict__ cnt, int* __restrict__ csr_src) {
    int e = blockIdx.x * blockDim.x + threadIdx.x;
    if (e >= N_EDGES) return;
    int src = ei[e], dst = ei[N_EDGES + e];
    int pos = atomicAdd(&cnt[dst], 1);
    atomicExch(&csr_src[rowptr[dst] + pos], src);
}

// ---------------- small dense prologue --------------------------------------

__global__ void k_climber(const float* __restrict__ climber,
                          const float* __restrict__ ln_g, const float* __restrict__ ln_b,
                          const float* __restrict__ W_c, const float* __restrict__ b_c,
                          float* __restrict__ c) {
    int g = blockIdx.x;
    int j = threadIdx.x;
    float v[6];
    float mu = 0.f;
    #pragma unroll
    for (int k = 0; k < 6; k++) { v[k] = climber[g*6+k]; mu += v[k]; }
    mu *= (1.f/6.f);
    float var = 0.f;
    #pragma unroll
    for (int k = 0; k < 6; k++) { float d = v[k]-mu; var += d*d; }
    var *= (1.f/6.f);
    float rs = rsqrtf(var + 1e-5f);
    float acc = b_c[j];
    #pragma unroll
    for (int k = 0; k < 6; k++) {
        float cn = (v[k]-mu)*rs*ln_g[k] + ln_b[k];
        acc += cn * W_c[k*64+j];
    }
    c[g*64+j] = fmaxf(acc, 0.f);
}

__global__ void k_film_coef(const float* __restrict__ c,
                            const float* __restrict__ Wf1, const float* __restrict__ bf1,
                            const float* __restrict__ Wf2, const float* __restrict__ bf2,
                            float* __restrict__ gb1, float* __restrict__ gb2) {
    int g = blockIdx.x;
    const float* Wf = blockIdx.y ? Wf2 : Wf1;
    const float* bf = blockIdx.y ? bf2 : bf1;
    float*       gb = blockIdx.y ? gb2 : gb1;
    int j = threadIdx.x;
    float acc = bf[j];
    #pragma unroll 8
    for (int k = 0; k < 64; k++)
        acc += c[g*64+k] * Wf[k*128+j];
    gb[g*128+j] = acc;
}

// ---------------- fused node kernels ----------------------------------------
// Layout: 4 nodes per wave, 16 lanes/node, lane sl holds features 4sl..4sl+3.

// GAT softmax-aggregate core: returns relu(sum alpha*z[src] + bg) for node i.
// First <=16 edge scores cached in registers (pass A), shuffled in pass B.
__device__ __forceinline__ float4 gat_core(int i, int sl,
    const int* __restrict__ rowptr, const int* __restrict__ csr_src,
    const float* __restrict__ es, const float* __restrict__ ed,
    const float* __restrict__ z, const float* __restrict__ bg) {
    int beg = rowptr[i], end = rowptr[i+1];
    int deg = end - beg;
    float edi = ed[i];

    float e_self = es[i] + edi;
    e_self = fmaxf(e_self, 0.2f * e_self);

    float sc = -1e30f; int sv0 = 0;
    if (sl < deg) {
        sv0 = csr_src[beg + sl];
        float v = es[sv0] + edi;
        sc = fmaxf(v, 0.2f * v);
    }
    float t = sc;
    for (int k = beg + 16 + sl; k < end; k += 16) {
        int s2 = csr_src[k];
        float v = es[s2] + edi;
        t = fmaxf(t, fmaxf(v, 0.2f * v));
    }
    #pragma unroll
    for (int off = 1; off < 16; off <<= 1)
        t = fmaxf(t, __shfl_xor(t, off, 16));
    float m = fmaxf(e_self, t);

    const float4* z4 = (const float4*)z;
    float ex = __expf(e_self - m);
    float s = ex;
    float4 zi = z4[i*16 + sl];
    float4 acc = {ex*zi.x, ex*zi.y, ex*zi.z, ex*zi.w};
    int lim = (deg < 16) ? deg : 16;
    for (int k = 0; k < lim; k++) {
        float scv = __shfl(sc, k, 16);
        int sv = __shfl(sv0, k, 16);
        float e2 = __expf(scv - m);
        s += e2;
        float4 zr = z4[sv*16 + sl];
        acc.x += e2*zr.x; acc.y += e2*zr.y; acc.z += e2*zr.z; acc.w += e2*zr.w;
    }
    for (int k = beg + 16; k < end; k++) {
        int sv = csr_src[k];
        float v = es[sv] + edi;
        v = fmaxf(v, 0.2f * v);
        float e2 = __expf(v - m);
        s += e2;
        float4 zr = z4[sv*16 + sl];
        acc.x += e2*zr.x; acc.y += e2*zr.y; acc.z += e2*zr.z; acc.w += e2*zr.w;
    }
    float inv = 1.f / (s + 1e-16f);
    float4 bg4 = ((const float4*)bg)[sl];
    float4 o;
    o.x = fmaxf(acc.x*inv + bg4.x, 0.f);
    o.y = fmaxf(acc.y*inv + bg4.y, 0.f);
    o.z = fmaxf(acc.z*inv + bg4.z, 0.f);
    o.w = fmaxf(acc.w*inv + bg4.w, 0.f);
    return o;
}

// row (float4/lane within 16-group) @ W[64x64] (staged in LDS as float4[64][16])
__device__ __forceinline__ float4 rowmat16(float4 hr, int sl, const float4* Wl) {
    float hv[4] = {hr.x, hr.y, hr.z, hr.w};
    float4 acc = {0.f, 0.f, 0.f, 0.f};
    #pragma unroll
    for (int k = 0; k < 64; k++) {
        float hk = __shfl(hv[k & 3], k >> 2, 16);
        float4 w = Wl[k*16 + sl];
        acc.x += hk*w.x; acc.y += hk*w.y; acc.z += hk*w.z; acc.w += hk*w.w;
    }
    return acc;
}

__device__ __forceinline__ void attn_proj(float4 zc, int sl,
    const float* __restrict__ a_src, const float* __restrict__ a_dst,
    int i, float* __restrict__ es, float* __restrict__ ed) {
    float4 as4 = ((const float4*)a_src)[sl];
    float4 ad4 = ((const float4*)a_dst)[sl];
    float ps = zc.x*as4.x + zc.y*as4.y + zc.z*as4.z + zc.w*as4.w;
    float pd = zc.x*ad4.x + zc.y*ad4.y + zc.z*ad4.z + zc.w*ad4.w;
    #pragma unroll
    for (int off = 1; off < 16; off <<= 1) {
        ps += __shfl_xor(ps, off, 16);
        pd += __shfl_xor(pd, off, 16);
    }
    if (sl == 0) { es[i] = ps; ed[i] = pd; }
}

// K1: h = film1(x[:, :6] @ W_in + b_in) ; z1 = h @ Wg1 ; es1/ed1
__global__ void k_layer1(const float* __restrict__ x, const int* __restrict__ batch,
                         const float* __restrict__ W_in, const float* __restrict__ b_in,
                         const float* __restrict__ gb1, const float* __restrict__ Wg1,
                         const float* __restrict__ as1, const float* __restrict__ ad1,
                         float* __restrict__ z1, float* __restrict__ es1,
                         float* __restrict__ ed1) {
    __shared__ float4 Wl[1024];
    const float4* Wg4 = (const float4*)Wg1;
    for (int t = threadIdx.x; t < 1024; t += blockDim.x) Wl[t] = Wg4[t];
    int tid = blockIdx.x * blockDim.x + threadIdx.x;
    int i  = tid >> 4;
    int sl = threadIdx.x & 15;
    __syncthreads();
    if (i >= N_NODES) return;
    float4 acc = ((const float4*)b_in)[sl];
    #pragma unroll
    for (int k = 0; k < 6; k++) {
        float xk = x[i*8+k];
        float4 w = ((const float4*)W_in)[k*16 + sl];
        acc.x += xk*w.x; acc.y += xk*w.y; acc.z += xk*w.z; acc.w += xk*w.w;
    }
    int g = batch[i];
    const float4* gb4 = (const float4*)gb1;
    float4 ga = gb4[g*32 + sl];
    float4 be = gb4[g*32 + 16 + sl];
    acc.x = acc.x*(1.f+ga.x) + be.x;
    acc.y = acc.y*(1.f+ga.y) + be.y;
    acc.z = acc.z*(1.f+ga.z) + be.z;
    acc.w = acc.w*(1.f+ga.w) + be.w;
    float4 zc = rowmat16(acc, sl, Wl);
    ((float4*)z1)[i*16 + sl] = zc;
    attn_proj(zc, sl, as1, ad1, i, es1, ed1);
}

// K2: h = film2(gat1(...)) ; z2 = h @ Wg2 ; es2/ed2
__global__ void k_layer2(const int* __restrict__ rowptr, const int* __restrict__ csr_src,
                         const float* __restrict__ es1, const float* __restrict__ ed1,
                         const float* __restrict__ z1, const float* __restrict__ bg1,
                         const int* __restrict__ batch, const float* __restrict__ gb2,
                         const float* __restrict__ Wg2, const float* __restrict__ as2,
                         const float* __restrict__ ad2,
                         float* __restrict__ z2, float* __restrict__ es2,
                         float* __restrict__ ed2) {
    __shared__ float4 Wl[1024];
    const float4* Wg4 = (const float4*)Wg2;
    for (int t = threadIdx.x; t < 1024; t += blockDim.x) Wl[t] = Wg4[t];
    int tid = blockIdx.x * blockDim.x + threadIdx.x;
    int i  = tid >> 4;
    int sl = threadIdx.x & 15;
    __syncthreads();
    if (i >= N_NODES) return;
    float4 o = gat_core(i, sl, rowptr, csr_src, es1, ed1, z1, bg1);
    int g = batch[i];
    const float4* gb4 = (const float4*)gb2;
    float4 ga = gb4[g*32 + sl];
    float4 be = gb4[g*32 + 16 + sl];
    o.x = o.x*(1.f+ga.x) + be.x;
    o.y = o.y*(1.f+ga.y) + be.y;
    o.z = o.z*(1.f+ga.z) + be.z;
    o.w = o.w*(1.f+ga.w) + be.w;
    float4 zc = rowmat16(o, sl, Wl);
    ((float4*)z2)[i*16 + sl] = zc;
    attn_proj(zc, sl, as2, ad2, i, es2, ed2);
}

// K3: h = gat2(...) ; out = (relu(h@Wc1+bc1)@Wc2+bc2) + 0.03*flag_head
__global__ void k_layer3(const int* __restrict__ rowptr, const int* __restrict__ csr_src,
                         const float* __restrict__ es2, const float* __restrict__ ed2,
                         const float* __restrict__ z2, const float* __restrict__ bg2,
                         const float* __restrict__ x,
                         const float* __restrict__ Wc1, const float* __restrict__ bc1,
                         const float* __restrict__ Wc2, const float* __restrict__ bc2,
                         const float* __restrict__ Wh1, const float* __restrict__ bh1,
                         const float* __restrict__ Wh2, const float* __restrict__ bh2,
                         float* __restrict__ out) {
    __shared__ float4 Wl[1024];
    const float4* Wc14 = (const float4*)Wc1;
    for (int t = threadIdx.x; t < 1024; t += blockDim.x) Wl[t] = Wc14[t];
    int tid = blockIdx.x * blockDim.x + threadIdx.x;
    int i  = tid >> 4;
    int sl = threadIdx.x & 15;
    __syncthreads();
    if (i >= N_NODES) return;
    float4 o = gat_core(i, sl, rowptr, csr_src, es2, ed2, z2, bg2);
    float4 acc = rowmat16(o, sl, Wl);
    float4 b4 = ((const float4*)bc1)[sl];
    acc.x = fmaxf(acc.x + b4.x, 0.f);
    acc.y = fmaxf(acc.y + b4.y, 0.f);
    acc.z = fmaxf(acc.z + b4.z, 0.f);
    acc.w = fmaxf(acc.w + b4.w, 0.f);
    const float4* Wc24 = (const float4*)Wc2;      // row j = Wc2[j][0..3]
    float4 r0 = Wc24[sl*4+0], r1 = Wc24[sl*4+1], r2 = Wc24[sl*4+2], r3 = Wc24[sl*4+3];
    float4 p;
    p.x = acc.x*r0.x + acc.y*r1.x + acc.z*r2.x + acc.w*r3.x;
    p.y = acc.x*r0.y + acc.y*r1.y + acc.z*r2.y + acc.w*r3.y;
    p.z = acc.x*r0.z + acc.y*r1.z + acc.z*r2.z + acc.w*r3.z;
    p.w = acc.x*r0.w + acc.y*r1.w + acc.z*r2.w + acc.w*r3.w;
    #pragma unroll
    for (int off = 1; off < 16; off <<= 1) {
        p.x += __shfl_xor(p.x, off, 16);
        p.y += __shfl_xor(p.y, off, 16);
        p.z += __shfl_xor(p.z, off, 16);
        p.w += __shfl_xor(p.w, off, 16);
    }
    if (sl == 0) {
        float f0 = x[i*8+6], f1 = x[i*8+7];
        float t8[8];
        #pragma unroll
        for (int q = 0; q < 8; q++)
            t8[q] = fmaxf(f0*Wh1[q] + f1*Wh1[8+q] + bh1[q], 0.f);
        float fl[4];
        #pragma unroll
        for (int q = 0; q < 4; q++) {
            float a = bh2[q];
            #pragma unroll
            for (int r = 0; r < 8; r++) a += t8[r]*Wh2[r*4+q];
            fl[q] = a;
        }
        float4 ov;
        ov.x = p.x + bc2[0] + 0.03f*fl[0];
        ov.y = p.y + bc2[1] + 0.03f*fl[1];
        ov.z = p.z + bc2[2] + 0.03f*fl[2];
        ov.w = p.w + bc2[3] + 0.03f*fl[3];
        ((float4*)out)[i] = ov;
    }
}

extern "C" void kernel_launch(void* const* d_in, const int* in_sizes, int n_in,
                              void* d_out, int out_size, void* d_ws, size_t ws_size,
                              hipStream_t stream) {
    const float* x       = (const float*)d_in[0];
    const int*   ei      = (const int*)  d_in[1];
    const int*   batch   = (const int*)  d_in[2];
    const float* climber = (const float*)d_in[3];
    const float* W_in    = (const float*)d_in[4];
    const float* b_in    = (const float*)d_in[5];
    const float* ln_g    = (const float*)d_in[6];
    const float* ln_b    = (const float*)d_in[7];
    const float* W_c     = (const float*)d_in[8];
    const float* b_c     = (const float*)d_in[9];
    const float* Wf1     = (const float*)d_in[10];
    const float* bf1     = (const float*)d_in[11];
    const float* Wf2     = (const float*)d_in[12];
    const float* bf2     = (const float*)d_in[13];
    const float* Wg1     = (const float*)d_in[14];
    const float* as1     = (const float*)d_in[15];
    const float* ad1     = (const float*)d_in[16];
    const float* bg1     = (const float*)d_in[17];
    const float* Wg2     = (const float*)d_in[18];
    const float* as2     = (const float*)d_in[19];
    const float* ad2     = (const float*)d_in[20];
    const float* bg2     = (const float*)d_in[21];
    const float* Wc1     = (const float*)d_in[22];
    const float* bc1     = (const float*)d_in[23];
    const float* Wc2     = (const float*)d_in[24];
    const float* bc2     = (const float*)d_in[25];
    const float* Wh1     = (const float*)d_in[26];
    const float* bh1     = (const float*)d_in[27];
    const float* Wh2     = (const float*)d_in[28];
    const float* bh2     = (const float*)d_in[29];
    float* out = (float*)d_out;
    float* ws  = (float*)d_ws;

    // workspace carve (~60 MB)
    float* c       = ws;                    // 64,000
    float* gb1     = c   + 64000;           // 128,000
    float* gb2     = gb1 + 128000;          // 128,000
    float* z1      = gb2 + 128000;          // 6,400,000
    float* z2      = z1  + 6400000;         // 6,400,000
    float* es1     = z2  + 6400000;         // 100,000
    float* ed1     = es1 + N_NODES;         // 100,000
    float* es2     = ed1 + N_NODES;         // 100,000
    float* ed2     = es2 + N_NODES;         // 100,000
    int*   deg     = (int*)(ed2 + N_NODES); // 100,000
    int*   cnt     = deg + N_NODES;         // 100,000
    int*   rowptr  = cnt + N_NODES;         // 100,001
    int*   csr_src = rowptr + N_NODES + 1;  // 1,200,000
    int*   part    = csr_src + N_EDGES;     // N_PART

    // CSR build (topology is layer-invariant)
    hipMemsetAsync(deg, 0, N_NODES*sizeof(int), stream);
    hipMemsetAsync(cnt, 0, N_NODES*sizeof(int), stream);
    int edgeBlocks = (N_EDGES + 255)/256;
    k_deg         <<<edgeBlocks, 256, 0, stream>>>(ei, deg);
    k_scan_partial<<<N_PART, SCAN_B, 0, stream>>>(deg, part);
    k_scan_part2  <<<1, 512, 0, stream>>>(part, rowptr);
    k_scan_final  <<<N_PART, SCAN_B, 0, stream>>>(deg, part, rowptr);
    k_scatter     <<<edgeBlocks, 256, 0, stream>>>(ei, rowptr, cnt, csr_src);

    // prologue
    k_climber<<<N_GRAPHS, 64, 0, stream>>>(climber, ln_g, ln_b, W_c, b_c, c);
    dim3 gB(N_GRAPHS, 2);
    k_film_coef<<<gB, 128, 0, stream>>>(c, Wf1, bf1, Wf2, bf2, gb1, gb2);

    int nodeBlocks = (N_NODES*16 + 255)/256;   // 6250
    k_layer1<<<nodeBlocks, 256, 0, stream>>>(x, batch, W_in, b_in, gb1, Wg1,
                                             as1, ad1, z1, es1, ed1);
    k_layer2<<<nodeBlocks, 256, 0, stream>>>(rowptr, csr_src, es1, ed1, z1, bg1,
                                             batch, gb2, Wg2, as2, ad2, z2, es2, ed2);
    k_layer3<<<nodeBlocks, 256, 0, stream>>>(rowptr, csr_src, es2, ed2, z2, bg2,
                                             x, Wc1, bc1, Wc2, bc2,
                                             Wh1, bh1, Wh2, bh2, out);
}

// Round 6
// 362.813 us; speedup vs baseline: 3.4676x; 1.2681x over previous
//
#include <hip/hip_runtime.h>
#include <math.h>

#define N_NODES 100000
#define N_EDGES 1200000
#define N_GRAPHS 1000
#define HID 64
#define NBUCK 256
#define NPB   391            // ceil(100000/256); 256*391 = 100096 >= 100000
#define EDGE_CHUNK 16384
#define S3_BLOCKS ((N_EDGES + EDGE_CHUNK - 1) / EDGE_CHUNK)   // 74

// ---------------- CSR build via 2-level bucket sort --------------------------

// S1: per-bucket edge histogram (LDS-aggregated)
__global__ void k_bhist(const int* __restrict__ ei, int* __restrict__ bucket_cnt) {
    __shared__ int hist[NBUCK];
    for (int t = threadIdx.x; t < NBUCK; t += blockDim.x) hist[t] = 0;
    __syncthreads();
    int e0 = blockIdx.x * EDGE_CHUNK;
    int e1 = min(e0 + EDGE_CHUNK, N_EDGES);
    for (int e = e0 + threadIdx.x; e < e1; e += blockDim.x)
        atomicAdd(&hist[ei[N_EDGES + e] / NPB], 1);
    __syncthreads();
    for (int t = threadIdx.x; t < NBUCK; t += blockDim.x)
        if (hist[t]) atomicAdd(&bucket_cnt[t], hist[t]);
}

// S2: single block scans 256 bucket counts -> bucket_base[0..256]
__global__ void k_bscan(const int* __restrict__ bucket_cnt, int* __restrict__ bucket_base) {
    __shared__ int sh[NBUCK];
    int t = threadIdx.x;
    int v = bucket_cnt[t];
    sh[t] = v;
    __syncthreads();
    for (int off = 1; off < NBUCK; off <<= 1) {
        int u = (t >= off) ? sh[t - off] : 0;
        __syncthreads();
        sh[t] += u;
        __syncthreads();
    }
    bucket_base[t] = sh[t] - v;               // exclusive
    if (t == NBUCK - 1) bucket_base[NBUCK] = sh[t];
}

// S3: binned scatter of (src,dst) pairs into bucket-major staging.
// Each block reserves contiguous per-bucket ranges -> near-full-line writes.
__global__ void k_bin(const int* __restrict__ ei, const int* __restrict__ bucket_base,
                      int* __restrict__ bucket_fill, int2* __restrict__ staged) {
    __shared__ int hist[NBUCK];
    __shared__ int cursor[NBUCK];
    for (int t = threadIdx.x; t < NBUCK; t += blockDim.x) hist[t] = 0;
    __syncthreads();
    int e0 = blockIdx.x * EDGE_CHUNK;
    int e1 = min(e0 + EDGE_CHUNK, N_EDGES);
    for (int e = e0 + threadIdx.x; e < e1; e += blockDim.x)
        atomicAdd(&hist[ei[N_EDGES + e] / NPB], 1);
    __syncthreads();
    if (threadIdx.x < NBUCK) {
        int hv = hist[threadIdx.x];
        int start = bucket_base[threadIdx.x];
        if (hv) start += atomicAdd(&bucket_fill[threadIdx.x], hv);
        cursor[threadIdx.x] = start;
    }
    __syncthreads();
    for (int e = e0 + threadIdx.x; e < e1; e += blockDim.x) {
        int src = ei[e], dst = ei[N_EDGES + e];
        int b = dst / NPB;
        int pos = atomicAdd(&cursor[b], 1);
        staged[pos] = make_int2(src, dst);
    }
}

// S4: one block per bucket: per-node deg + local scan -> rowptr, then scatter
// srcs into the bucket's contiguous csr region (block-local writes).
__global__ void k_bcsr(const int2* __restrict__ staged, const int* __restrict__ bucket_base,
                       int* __restrict__ rowptr, int* __restrict__ csr_src) {
    __shared__ int ldeg[NPB];
    __shared__ int sc[512];
    __shared__ int cursor[NPB];
    int b = blockIdx.x;
    int n0 = b * NPB;
    int n1 = min(n0 + NPB, N_NODES);
    int nn = n1 - n0;
    int bbase = bucket_base[b];
    int bcnt  = bucket_base[b+1] - bbase;
    for (int t = threadIdx.x; t < NPB; t += blockDim.x) ldeg[t] = 0;
    __syncthreads();
    for (int k = threadIdx.x; k < bcnt; k += blockDim.x)
        atomicAdd(&ldeg[staged[bbase + k].y - n0], 1);
    __syncthreads();
    // inclusive scan over 512 (padded)
    if (threadIdx.x < 512) sc[threadIdx.x] = (threadIdx.x < nn) ? ldeg[threadIdx.x] : 0;
    __syncthreads();
    for (int off = 1; off < 512; off <<= 1) {
        int u = 0;
        if (threadIdx.x < 512 && threadIdx.x >= off) u = sc[threadIdx.x - off];
        __syncthreads();
        if (threadIdx.x < 512) sc[threadIdx.x] += u;
        __syncthreads();
    }
    if (threadIdx.x < nn) {
        int pre = sc[threadIdx.x] - ldeg[threadIdx.x];     // exclusive
        rowptr[n0 + threadIdx.x] = bbase + pre;
        cursor[threadIdx.x] = bbase + pre;
    }
    if (b == 0 && threadIdx.x == 0) rowptr[N_NODES] = bucket_base[NBUCK];
    __syncthreads();
    for (int k = threadIdx.x; k < bcnt; k += blockDim.x) {
        int2 ed = staged[bbase + k];
        int pos = atomicAdd(&cursor[ed.y - n0], 1);
        csr_src[pos] = ed.x;
    }
}

// ---------------- small dense prologue --------------------------------------

__global__ void k_climber(const float* __restrict__ climber,
                          const float* __restrict__ ln_g, const float* __restrict__ ln_b,
                          const float* __restrict__ W_c, const float* __restrict__ b_c,
                          float* __restrict__ c) {
    int g = blockIdx.x;
    int j = threadIdx.x;
    float v[6];
    float mu = 0.f;
    #pragma unroll
    for (int k = 0; k < 6; k++) { v[k] = climber[g*6+k]; mu += v[k]; }
    mu *= (1.f/6.f);
    float var = 0.f;
    #pragma unroll
    for (int k = 0; k < 6; k++) { float d = v[k]-mu; var += d*d; }
    var *= (1.f/6.f);
    float rs = rsqrtf(var + 1e-5f);
    float acc = b_c[j];
    #pragma unroll
    for (int k = 0; k < 6; k++) {
        float cn = (v[k]-mu)*rs*ln_g[k] + ln_b[k];
        acc += cn * W_c[k*64+j];
    }
    c[g*64+j] = fmaxf(acc, 0.f);
}

__global__ void k_film_coef(const float* __restrict__ c,
                            const float* __restrict__ Wf1, const float* __restrict__ bf1,
                            const float* __restrict__ Wf2, const float* __restrict__ bf2,
                            float* __restrict__ gb1, float* __restrict__ gb2) {
    int g = blockIdx.x;
    const float* Wf = blockIdx.y ? Wf2 : Wf1;
    const float* bf = blockIdx.y ? bf2 : bf1;
    float*       gb = blockIdx.y ? gb2 : gb1;
    int j = threadIdx.x;
    float acc = bf[j];
    #pragma unroll 8
    for (int k = 0; k < 64; k++)
        acc += c[g*64+k] * Wf[k*128+j];
    gb[g*128+j] = acc;
}

// ---------------- fused node kernels ----------------------------------------
// Layout: 4 nodes per wave, 16 lanes/node, lane sl holds features 4sl..4sl+3.

__device__ __forceinline__ float4 gat_core(int i, int sl,
    const int* __restrict__ rowptr, const int* __restrict__ csr_src,
    const float* __restrict__ es, const float* __restrict__ ed,
    const float* __restrict__ z, const float* __restrict__ bg) {
    int beg = rowptr[i], end = rowptr[i+1];
    int deg = end - beg;
    float edi = ed[i];

    float e_self = es[i] + edi;
    e_self = fmaxf(e_self, 0.2f * e_self);

    float sc = -1e30f; int sv0 = 0;
    if (sl < deg) {
        sv0 = csr_src[beg + sl];
        float v = es[sv0] + edi;
        sc = fmaxf(v, 0.2f * v);
    }
    float t = sc;
    for (int k = beg + 16 + sl; k < end; k += 16) {
        int s2 = csr_src[k];
        float v = es[s2] + edi;
        t = fmaxf(t, fmaxf(v, 0.2f * v));
    }
    #pragma unroll
    for (int off = 1; off < 16; off <<= 1)
        t = fmaxf(t, __shfl_xor(t, off, 16));
    float m = fmaxf(e_self, t);

    const float4* z4 = (const float4*)z;
    float ex = __expf(e_self - m);
    float s = ex;
    float4 zi = z4[i*16 + sl];
    float4 acc = {ex*zi.x, ex*zi.y, ex*zi.z, ex*zi.w};
    int lim = (deg < 16) ? deg : 16;
    for (int k = 0; k < lim; k++) {
        float scv = __shfl(sc, k, 16);
        int sv = __shfl(sv0, k, 16);
        float e2 = __expf(scv - m);
        s += e2;
        float4 zr = z4[sv*16 + sl];
        acc.x += e2*zr.x; acc.y += e2*zr.y; acc.z += e2*zr.z; acc.w += e2*zr.w;
    }
    for (int k = beg + 16; k < end; k++) {
        int sv = csr_src[k];
        float v = es[sv] + edi;
        v = fmaxf(v, 0.2f * v);
        float e2 = __expf(v - m);
        s += e2;
        float4 zr = z4[sv*16 + sl];
        acc.x += e2*zr.x; acc.y += e2*zr.y; acc.z += e2*zr.z; acc.w += e2*zr.w;
    }
    float inv = 1.f / (s + 1e-16f);
    float4 bg4 = ((const float4*)bg)[sl];
    float4 o;
    o.x = fmaxf(acc.x*inv + bg4.x, 0.f);
    o.y = fmaxf(acc.y*inv + bg4.y, 0.f);
    o.z = fmaxf(acc.z*inv + bg4.z, 0.f);
    o.w = fmaxf(acc.w*inv + bg4.w, 0.f);
    return o;
}

__device__ __forceinline__ float4 rowmat16(float4 hr, int sl, const float4* Wl) {
    float hv[4] = {hr.x, hr.y, hr.z, hr.w};
    float4 acc = {0.f, 0.f, 0.f, 0.f};
    #pragma unroll
    for (int k = 0; k < 64; k++) {
        float hk = __shfl(hv[k & 3], k >> 2, 16);
        float4 w = Wl[k*16 + sl];
        acc.x += hk*w.x; acc.y += hk*w.y; acc.z += hk*w.z; acc.w += hk*w.w;
    }
    return acc;
}

__device__ __forceinline__ void attn_proj(float4 zc, int sl,
    const float* __restrict__ a_src, const float* __restrict__ a_dst,
    int i, float* __restrict__ es, float* __restrict__ ed) {
    float4 as4 = ((const float4*)a_src)[sl];
    float4 ad4 = ((const float4*)a_dst)[sl];
    float ps = zc.x*as4.x + zc.y*as4.y + zc.z*as4.z + zc.w*as4.w;
    float pd = zc.x*ad4.x + zc.y*ad4.y + zc.z*ad4.z + zc.w*ad4.w;
    #pragma unroll
    for (int off = 1; off < 16; off <<= 1) {
        ps += __shfl_xor(ps, off, 16);
        pd += __shfl_xor(pd, off, 16);
    }
    if (sl == 0) { es[i] = ps; ed[i] = pd; }
}

__global__ void k_layer1(const float* __restrict__ x, const int* __restrict__ batch,
                         const float* __restrict__ W_in, const float* __restrict__ b_in,
                         const float* __restrict__ gb1, const float* __restrict__ Wg1,
                         const float* __restrict__ as1, const float* __restrict__ ad1,
                         float* __restrict__ z1, float* __restrict__ es1,
                         float* __restrict__ ed1) {
    __shared__ float4 Wl[1024];
    const float4* Wg4 = (const float4*)Wg1;
    for (int t = threadIdx.x; t < 1024; t += blockDim.x) Wl[t] = Wg4[t];
    int tid = blockIdx.x * blockDim.x + threadIdx.x;
    int i  = tid >> 4;
    int sl = threadIdx.x & 15;
    __syncthreads();
    if (i >= N_NODES) return;
    float4 acc = ((const float4*)b_in)[sl];
    #pragma unroll
    for (int k = 0; k < 6; k++) {
        float xk = x[i*8+k];
        float4 w = ((const float4*)W_in)[k*16 + sl];
        acc.x += xk*w.x; acc.y += xk*w.y; acc.z += xk*w.z; acc.w += xk*w.w;
    }
    int g = batch[i];
    const float4* gb4 = (const float4*)gb1;
    float4 ga = gb4[g*32 + sl];
    float4 be = gb4[g*32 + 16 + sl];
    acc.x = acc.x*(1.f+ga.x) + be.x;
    acc.y = acc.y*(1.f+ga.y) + be.y;
    acc.z = acc.z*(1.f+ga.z) + be.z;
    acc.w = acc.w*(1.f+ga.w) + be.w;
    float4 zc = rowmat16(acc, sl, Wl);
    ((float4*)z1)[i*16 + sl] = zc;
    attn_proj(zc, sl, as1, ad1, i, es1, ed1);
}

__global__ void k_layer2(const int* __restrict__ rowptr, const int* __restrict__ csr_src,
                         const float* __restrict__ es1, const float* __restrict__ ed1,
                         const float* __restrict__ z1, const float* __restrict__ bg1,
                         const int* __restrict__ batch, const float* __restrict__ gb2,
                         const float* __restrict__ Wg2, const float* __restrict__ as2,
                         const float* __restrict__ ad2,
                         float* __restrict__ z2, float* __restrict__ es2,
                         float* __restrict__ ed2) {
    __shared__ float4 Wl[1024];
    const float4* Wg4 = (const float4*)Wg2;
    for (int t = threadIdx.x; t < 1024; t += blockDim.x) Wl[t] = Wg4[t];
    int tid = blockIdx.x * blockDim.x + threadIdx.x;
    int i  = tid >> 4;
    int sl = threadIdx.x & 15;
    __syncthreads();
    if (i >= N_NODES) return;
    float4 o = gat_core(i, sl, rowptr, csr_src, es1, ed1, z1, bg1);
    int g = batch[i];
    const float4* gb4 = (const float4*)gb2;
    float4 ga = gb4[g*32 + sl];
    float4 be = gb4[g*32 + 16 + sl];
    o.x = o.x*(1.f+ga.x) + be.x;
    o.y = o.y*(1.f+ga.y) + be.y;
    o.z = o.z*(1.f+ga.z) + be.z;
    o.w = o.w*(1.f+ga.w) + be.w;
    float4 zc = rowmat16(o, sl, Wl);
    ((float4*)z2)[i*16 + sl] = zc;
    attn_proj(zc, sl, as2, ad2, i, es2, ed2);
}

__global__ void k_layer3(const int* __restrict__ rowptr, const int* __restrict__ csr_src,
                         const float* __restrict__ es2, const float* __restrict__ ed2,
                         const float* __restrict__ z2, const float* __restrict__ bg2,
                         const float* __restrict__ x,
                         const float* __restrict__ Wc1, const float* __restrict__ bc1,
                         const float* __restrict__ Wc2, const float* __restrict__ bc2,
                         const float* __restrict__ Wh1, const float* __restrict__ bh1,
                         const float* __restrict__ Wh2, const float* __restrict__ bh2,
                         float* __restrict__ out) {
    __shared__ float4 Wl[1024];
    const float4* Wc14 = (const float4*)Wc1;
    for (int t = threadIdx.x; t < 1024; t += blockDim.x) Wl[t] = Wc14[t];
    int tid = blockIdx.x * blockDim.x + threadIdx.x;
    int i  = tid >> 4;
    int sl = threadIdx.x & 15;
    __syncthreads();
    if (i >= N_NODES) return;
    float4 o = gat_core(i, sl, rowptr, csr_src, es2, ed2, z2, bg2);
    float4 acc = rowmat16(o, sl, Wl);
    float4 b4 = ((const float4*)bc1)[sl];
    acc.x = fmaxf(acc.x + b4.x, 0.f);
    acc.y = fmaxf(acc.y + b4.y, 0.f);
    acc.z = fmaxf(acc.z + b4.z, 0.f);
    acc.w = fmaxf(acc.w + b4.w, 0.f);
    const float4* Wc24 = (const float4*)Wc2;
    float4 r0 = Wc24[sl*4+0], r1 = Wc24[sl*4+1], r2 = Wc24[sl*4+2], r3 = Wc24[sl*4+3];
    float4 p;
    p.x = acc.x*r0.x + acc.y*r1.x + acc.z*r2.x + acc.w*r3.x;
    p.y = acc.x*r0.y + acc.y*r1.y + acc.z*r2.y + acc.w*r3.y;
    p.z = acc.x*r0.z + acc.y*r1.z + acc.z*r2.z + acc.w*r3.z;
    p.w = acc.x*r0.w + acc.y*r1.w + acc.z*r2.w + acc.w*r3.w;
    #pragma unroll
    for (int off = 1; off < 16; off <<= 1) {
        p.x += __shfl_xor(p.x, off, 16);
        p.y += __shfl_xor(p.y, off, 16);
        p.z += __shfl_xor(p.z, off, 16);
        p.w += __shfl_xor(p.w, off, 16);
    }
    if (sl == 0) {
        float f0 = x[i*8+6], f1 = x[i*8+7];
        float t8[8];
        #pragma unroll
        for (int q = 0; q < 8; q++)
            t8[q] = fmaxf(f0*Wh1[q] + f1*Wh1[8+q] + bh1[q], 0.f);
        float fl[4];
        #pragma unroll
        for (int q = 0; q < 4; q++) {
            float a = bh2[q];
            #pragma unroll
            for (int r = 0; r < 8; r++) a += t8[r]*Wh2[r*4+q];
            fl[q] = a;
        }
        float4 ov;
        ov.x = p.x + bc2[0] + 0.03f*fl[0];
        ov.y = p.y + bc2[1] + 0.03f*fl[1];
        ov.z = p.z + bc2[2] + 0.03f*fl[2];
        ov.w = p.w + bc2[3] + 0.03f*fl[3];
        ((float4*)out)[i] = ov;
    }
}

extern "C" void kernel_launch(void* const* d_in, const int* in_sizes, int n_in,
                              void* d_out, int out_size, void* d_ws, size_t ws_size,
                              hipStream_t stream) {
    const float* x       = (const float*)d_in[0];
    const int*   ei      = (const int*)  d_in[1];
    const int*   batch   = (const int*)  d_in[2];
    const float* climber = (const float*)d_in[3];
    const float* W_in    = (const float*)d_in[4];
    const float* b_in    = (const float*)d_in[5];
    const float* ln_g    = (const float*)d_in[6];
    const float* ln_b    = (const float*)d_in[7];
    const float* W_c     = (const float*)d_in[8];
    const float* b_c     = (const float*)d_in[9];
    const float* Wf1     = (const float*)d_in[10];
    const float* bf1     = (const float*)d_in[11];
    const float* Wf2     = (const float*)d_in[12];
    const float* bf2     = (const float*)d_in[13];
    const float* Wg1     = (const float*)d_in[14];
    const float* as1     = (const float*)d_in[15];
    const float* ad1     = (const float*)d_in[16];
    const float* bg1     = (const float*)d_in[17];
    const float* Wg2     = (const float*)d_in[18];
    const float* as2     = (const float*)d_in[19];
    const float* ad2     = (const float*)d_in[20];
    const float* bg2     = (const float*)d_in[21];
    const float* Wc1     = (const float*)d_in[22];
    const float* bc1     = (const float*)d_in[23];
    const float* Wc2     = (const float*)d_in[24];
    const float* bc2     = (const float*)d_in[25];
    const float* Wh1     = (const float*)d_in[26];
    const float* bh1     = (const float*)d_in[27];
    const float* Wh2     = (const float*)d_in[28];
    const float* bh2     = (const float*)d_in[29];
    float* out = (float*)d_out;
    float* ws  = (float*)d_ws;

    // workspace carve (~69 MB)
    float* c           = ws;                    // 64,000
    float* gb1         = c   + 64000;           // 128,000
    float* gb2         = gb1 + 128000;          // 128,000
    float* z1          = gb2 + 128000;          // 6,400,000
    float* z2          = z1  + 6400000;         // 6,400,000
    float* es1         = z2  + 6400000;         // 100,000
    float* ed1         = es1 + N_NODES;         // 100,000
    float* es2         = ed1 + N_NODES;         // 100,000
    float* ed2         = es2 + N_NODES;         // 100,000
    int*   rowptr      = (int*)(ed2 + N_NODES); // 100,001
    int*   csr_src     = rowptr + N_NODES + 1;  // 1,200,000
    int*   bucket_cnt  = csr_src + N_EDGES;     // 256
    int*   bucket_base = bucket_cnt + NBUCK;    // 257
    int*   bucket_fill = bucket_base + NBUCK+1; // 256
    int2*  staged      = (int2*)(bucket_fill + NBUCK + 1); // 1,200,000 int2

    // CSR build via bucket sort (topology is layer-invariant)
    hipMemsetAsync(bucket_cnt,  0, NBUCK*sizeof(int), stream);
    hipMemsetAsync(bucket_fill, 0, NBUCK*sizeof(int), stream);
    k_bhist<<<S3_BLOCKS, 1024, 0, stream>>>(ei, bucket_cnt);
    k_bscan<<<1, NBUCK, 0, stream>>>(bucket_cnt, bucket_base);
    k_bin  <<<S3_BLOCKS, 1024, 0, stream>>>(ei, bucket_base, bucket_fill, staged);
    k_bcsr <<<NBUCK, 1024, 0, stream>>>(staged, bucket_base, rowptr, csr_src);

    // prologue
    k_climber<<<N_GRAPHS, 64, 0, stream>>>(climber, ln_g, ln_b, W_c, b_c, c);
    dim3 gB(N_GRAPHS, 2);
    k_film_coef<<<gB, 128, 0, stream>>>(c, Wf1, bf1, Wf2, bf2, gb1, gb2);

    int nodeBlocks = (N_NODES*16 + 255)/256;   // 6250
    k_layer1<<<nodeBlocks, 256, 0, stream>>>(x, batch, W_in, b_in, gb1, Wg1,
                                             as1, ad1, z1, es1, ed1);
    k_layer2<<<nodeBlocks, 256, 0, stream>>>(rowptr, csr_src, es1, ed1, z1, bg1,
                                             batch, gb2, Wg2, as2, ad2, z2, es2, ed2);
    k_layer3<<<nodeBlocks, 256, 0, stream>>>(rowptr, csr_src, es2, ed2, z2, bg2,
                                             x, Wc1, bc1, Wc2, bc2,
                                             Wh1, bh1, Wh2, bh2, out);
}

// Round 7
// 343.346 us; speedup vs baseline: 3.6643x; 1.0567x over previous
//
#include <hip/hip_runtime.h>
#include <math.h>

#define N_NODES 100000
#define N_EDGES 1200000
#define N_GRAPHS 1000
#define HID 64
#define NBUCK 256
#define NPB   391            // ceil(100000/256); 256*391 = 100096 >= 100000
#define EDGE_CHUNK 16384
#define S3_BLOCKS ((N_EDGES + EDGE_CHUNK - 1) / EDGE_CHUNK)   // 74

// ---------------- CSR build via 2-level bucket sort --------------------------

__global__ void k_bhist(const int* __restrict__ ei, int* __restrict__ bucket_cnt) {
    __shared__ int hist[NBUCK];
    for (int t = threadIdx.x; t < NBUCK; t += blockDim.x) hist[t] = 0;
    __syncthreads();
    int e0 = blockIdx.x * EDGE_CHUNK;
    int e1 = min(e0 + EDGE_CHUNK, N_EDGES);
    for (int e = e0 + threadIdx.x; e < e1; e += blockDim.x)
        atomicAdd(&hist[ei[N_EDGES + e] / NPB], 1);
    __syncthreads();
    for (int t = threadIdx.x; t < NBUCK; t += blockDim.x)
        if (hist[t]) atomicAdd(&bucket_cnt[t], hist[t]);
}

__global__ void k_bscan(const int* __restrict__ bucket_cnt, int* __restrict__ bucket_base) {
    __shared__ int sh[NBUCK];
    int t = threadIdx.x;
    int v = bucket_cnt[t];
    sh[t] = v;
    __syncthreads();
    for (int off = 1; off < NBUCK; off <<= 1) {
        int u = (t >= off) ? sh[t - off] : 0;
        __syncthreads();
        sh[t] += u;
        __syncthreads();
    }
    bucket_base[t] = sh[t] - v;               // exclusive
    if (t == NBUCK - 1) bucket_base[NBUCK] = sh[t];
}

__global__ void k_bin(const int* __restrict__ ei, const int* __restrict__ bucket_base,
                      int* __restrict__ bucket_fill, int2* __restrict__ staged) {
    __shared__ int hist[NBUCK];
    __shared__ int cursor[NBUCK];
    for (int t = threadIdx.x; t < NBUCK; t += blockDim.x) hist[t] = 0;
    __syncthreads();
    int e0 = blockIdx.x * EDGE_CHUNK;
    int e1 = min(e0 + EDGE_CHUNK, N_EDGES);
    for (int e = e0 + threadIdx.x; e < e1; e += blockDim.x)
        atomicAdd(&hist[ei[N_EDGES + e] / NPB], 1);
    __syncthreads();
    if (threadIdx.x < NBUCK) {
        int hv = hist[threadIdx.x];
        int start = bucket_base[threadIdx.x];
        if (hv) start += atomicAdd(&bucket_fill[threadIdx.x], hv);
        cursor[threadIdx.x] = start;
    }
    __syncthreads();
    for (int e = e0 + threadIdx.x; e < e1; e += blockDim.x) {
        int src = ei[e], dst = ei[N_EDGES + e];
        int b = dst / NPB;
        int pos = atomicAdd(&cursor[b], 1);
        staged[pos] = make_int2(src, dst);
    }
}

__global__ void k_bcsr(const int2* __restrict__ staged, const int* __restrict__ bucket_base,
                       int* __restrict__ rowptr, int* __restrict__ csr_src) {
    __shared__ int ldeg[NPB];
    __shared__ int sc[512];
    __shared__ int cursor[NPB];
    int b = blockIdx.x;
    int n0 = b * NPB;
    int n1 = min(n0 + NPB, N_NODES);
    int nn = n1 - n0;
    int bbase = bucket_base[b];
    int bcnt  = bucket_base[b+1] - bbase;
    for (int t = threadIdx.x; t < NPB; t += blockDim.x) ldeg[t] = 0;
    __syncthreads();
    for (int k = threadIdx.x; k < bcnt; k += blockDim.x)
        atomicAdd(&ldeg[staged[bbase + k].y - n0], 1);
    __syncthreads();
    if (threadIdx.x < 512) sc[threadIdx.x] = (threadIdx.x < nn) ? ldeg[threadIdx.x] : 0;
    __syncthreads();
    for (int off = 1; off < 512; off <<= 1) {
        int u = 0;
        if (threadIdx.x < 512 && threadIdx.x >= off) u = sc[threadIdx.x - off];
        __syncthreads();
        if (threadIdx.x < 512) sc[threadIdx.x] += u;
        __syncthreads();
    }
    if (threadIdx.x < nn) {
        int pre = sc[threadIdx.x] - ldeg[threadIdx.x];     // exclusive
        rowptr[n0 + threadIdx.x] = bbase + pre;
        cursor[threadIdx.x] = bbase + pre;
    }
    if (b == 0 && threadIdx.x == 0) rowptr[N_NODES] = bucket_base[NBUCK];
    __syncthreads();
    for (int k = threadIdx.x; k < bcnt; k += blockDim.x) {
        int2 ed = staged[bbase + k];
        int pos = atomicAdd(&cursor[ed.y - n0], 1);
        csr_src[pos] = ed.x;
    }
}

// ---------------- small dense prologue --------------------------------------

__global__ void k_climber(const float* __restrict__ climber,
                          const float* __restrict__ ln_g, const float* __restrict__ ln_b,
                          const float* __restrict__ W_c, const float* __restrict__ b_c,
                          float* __restrict__ c) {
    int g = blockIdx.x;
    int j = threadIdx.x;
    float v[6];
    float mu = 0.f;
    #pragma unroll
    for (int k = 0; k < 6; k++) { v[k] = climber[g*6+k]; mu += v[k]; }
    mu *= (1.f/6.f);
    float var = 0.f;
    #pragma unroll
    for (int k = 0; k < 6; k++) { float d = v[k]-mu; var += d*d; }
    var *= (1.f/6.f);
    float rs = rsqrtf(var + 1e-5f);
    float acc = b_c[j];
    #pragma unroll
    for (int k = 0; k < 6; k++) {
        float cn = (v[k]-mu)*rs*ln_g[k] + ln_b[k];
        acc += cn * W_c[k*64+j];
    }
    c[g*64+j] = fmaxf(acc, 0.f);
}

__global__ void k_film_coef(const float* __restrict__ c,
                            const float* __restrict__ Wf1, const float* __restrict__ bf1,
                            const float* __restrict__ Wf2, const float* __restrict__ bf2,
                            float* __restrict__ gb1, float* __restrict__ gb2) {
    int g = blockIdx.x;
    const float* Wf = blockIdx.y ? Wf2 : Wf1;
    const float* bf = blockIdx.y ? bf2 : bf1;
    float*       gb = blockIdx.y ? gb2 : gb1;
    int j = threadIdx.x;
    float acc = bf[j];
    #pragma unroll 8
    for (int k = 0; k < 64; k++)
        acc += c[g*64+k] * Wf[k*128+j];
    gb[g*128+j] = acc;
}

// ---------------- fused node kernels ----------------------------------------
// Layout: 4 nodes per wave, 16 lanes/node, lane sl holds features 4sl..4sl+3.

// GAT softmax-aggregate core. First <=32 edges cached in registers (2 banks);
// pass B unrolled by 4 with batched row-gathers for memory-level parallelism.
__device__ __forceinline__ float4 gat_core(int i, int sl,
    const int* __restrict__ rowptr, const int* __restrict__ csr_src,
    const float* __restrict__ es, const float* __restrict__ ed,
    const float* __restrict__ z, const float* __restrict__ bg) {
    int beg = rowptr[i], end = rowptr[i+1];
    int deg = end - beg;
    float edi = ed[i];

    float e_self = es[i] + edi;
    e_self = fmaxf(e_self, 0.2f * e_self);

    // cache up to 32 edges: bank A = edges [0,16), bank B = [16,32)
    int svA = 0, svB = 0;
    float scA = -1e30f, scB = -1e30f;
    if (sl < deg) {
        svA = csr_src[beg + sl];
        float v = es[svA] + edi;
        scA = fmaxf(v, 0.2f * v);
    }
    if (16 + sl < deg) {
        svB = csr_src[beg + 16 + sl];
        float v = es[svB] + edi;
        scB = fmaxf(v, 0.2f * v);
    }
    float t = fmaxf(scA, scB);
    for (int k = beg + 32 + sl; k < end; k += 16) {   // rare: deg > 32
        int s2 = csr_src[k];
        float v = es[s2] + edi;
        t = fmaxf(t, fmaxf(v, 0.2f * v));
    }
    #pragma unroll
    for (int off = 1; off < 16; off <<= 1)
        t = fmaxf(t, __shfl_xor(t, off, 16));
    float m = fmaxf(e_self, t);

    const float4* z4 = (const float4*)z;
    float ex = __expf(e_self - m);
    float s = ex;
    float4 zi = z4[i*16 + sl];
    float4 acc = {ex*zi.x, ex*zi.y, ex*zi.z, ex*zi.w};

    int lim = (deg < 32) ? deg : 32;
    int k = 0;
    // unroll-4: four independent row-gathers in flight per step
    for (; k + 4 <= lim; k += 4) {
        int a0, a1, a2, a3;
        float c0, c1, c2, c3;
        if (k < 16) {            // block [k,k+3] fully in bank A (16 % 4 == 0)
            a0 = __shfl(svA, k+0, 16); c0 = __shfl(scA, k+0, 16);
            a1 = __shfl(svA, k+1, 16); c1 = __shfl(scA, k+1, 16);
            a2 = __shfl(svA, k+2, 16); c2 = __shfl(scA, k+2, 16);
            a3 = __shfl(svA, k+3, 16); c3 = __shfl(scA, k+3, 16);
        } else {
            a0 = __shfl(svB, k-16, 16); c0 = __shfl(scB, k-16, 16);
            a1 = __shfl(svB, k-15, 16); c1 = __shfl(scB, k-15, 16);
            a2 = __shfl(svB, k-14, 16); c2 = __shfl(scB, k-14, 16);
            a3 = __shfl(svB, k-13, 16); c3 = __shfl(scB, k-13, 16);
        }
        float4 r0 = z4[a0*16 + sl];
        float4 r1 = z4[a1*16 + sl];
        float4 r2 = z4[a2*16 + sl];
        float4 r3 = z4[a3*16 + sl];
        float e0 = __expf(c0 - m);
        float e1 = __expf(c1 - m);
        float e2 = __expf(c2 - m);
        float e3 = __expf(c3 - m);
        s += (e0 + e1) + (e2 + e3);
        acc.x += e0*r0.x + e1*r1.x + e2*r2.x + e3*r3.x;
        acc.y += e0*r0.y + e1*r1.y + e2*r2.y + e3*r3.y;
        acc.z += e0*r0.z + e1*r1.z + e2*r2.z + e3*r3.z;
        acc.w += e0*r0.w + e1*r1.w + e2*r2.w + e3*r3.w;
    }
    for (; k < lim; k++) {
        int a; float cv;
        if (k < 16) { a = __shfl(svA, k, 16);    cv = __shfl(scA, k, 16); }
        else        { a = __shfl(svB, k-16, 16); cv = __shfl(scB, k-16, 16); }
        float e2 = __expf(cv - m);
        s += e2;
        float4 zr = z4[a*16 + sl];
        acc.x += e2*zr.x; acc.y += e2*zr.y; acc.z += e2*zr.z; acc.w += e2*zr.w;
    }
    for (int kk = beg + 32; kk < end; kk++) {   // rare fallback
        int sv = csr_src[kk];
        float v = es[sv] + edi;
        v = fmaxf(v, 0.2f * v);
        float e2 = __expf(v - m);
        s += e2;
        float4 zr = z4[sv*16 + sl];
        acc.x += e2*zr.x; acc.y += e2*zr.y; acc.z += e2*zr.z; acc.w += e2*zr.w;
    }
    float inv = 1.f / (s + 1e-16f);
    float4 bg4 = ((const float4*)bg)[sl];
    float4 o;
    o.x = fmaxf(acc.x*inv + bg4.x, 0.f);
    o.y = fmaxf(acc.y*inv + bg4.y, 0.f);
    o.z = fmaxf(acc.z*inv + bg4.z, 0.f);
    o.w = fmaxf(acc.w*inv + bg4.w, 0.f);
    return o;
}

__device__ __forceinline__ float4 rowmat16(float4 hr, int sl, const float4* Wl) {
    float hv[4] = {hr.x, hr.y, hr.z, hr.w};
    float4 acc = {0.f, 0.f, 0.f, 0.f};
    #pragma unroll
    for (int k = 0; k < 64; k++) {
        float hk = __shfl(hv[k & 3], k >> 2, 16);
        float4 w = Wl[k*16 + sl];
        acc.x += hk*w.x; acc.y += hk*w.y; acc.z += hk*w.z; acc.w += hk*w.w;
    }
    return acc;
}

__device__ __forceinline__ void attn_proj(float4 zc, int sl,
    const float* __restrict__ a_src, const float* __restrict__ a_dst,
    int i, float* __restrict__ es, float* __restrict__ ed) {
    float4 as4 = ((const float4*)a_src)[sl];
    float4 ad4 = ((const float4*)a_dst)[sl];
    float ps = zc.x*as4.x + zc.y*as4.y + zc.z*as4.z + zc.w*as4.w;
    float pd = zc.x*ad4.x + zc.y*ad4.y + zc.z*ad4.z + zc.w*ad4.w;
    #pragma unroll
    for (int off = 1; off < 16; off <<= 1) {
        ps += __shfl_xor(ps, off, 16);
        pd += __shfl_xor(pd, off, 16);
    }
    if (sl == 0) { es[i] = ps; ed[i] = pd; }
}

__global__ void k_layer1(const float* __restrict__ x, const int* __restrict__ batch,
                         const float* __restrict__ W_in, const float* __restrict__ b_in,
                         const float* __restrict__ gb1, const float* __restrict__ Wg1,
                         const float* __restrict__ as1, const float* __restrict__ ad1,
                         float* __restrict__ z1, float* __restrict__ es1,
                         float* __restrict__ ed1) {
    __shared__ float4 Wl[1024];
    const float4* Wg4 = (const float4*)Wg1;
    for (int t = threadIdx.x; t < 1024; t += blockDim.x) Wl[t] = Wg4[t];
    int tid = blockIdx.x * blockDim.x + threadIdx.x;
    int i  = tid >> 4;
    int sl = threadIdx.x & 15;
    __syncthreads();
    if (i >= N_NODES) return;
    float4 acc = ((const float4*)b_in)[sl];
    #pragma unroll
    for (int k = 0; k < 6; k++) {
        float xk = x[i*8+k];
        float4 w = ((const float4*)W_in)[k*16 + sl];
        acc.x += xk*w.x; acc.y += xk*w.y; acc.z += xk*w.z; acc.w += xk*w.w;
    }
    int g = batch[i];
    const float4* gb4 = (const float4*)gb1;
    float4 ga = gb4[g*32 + sl];
    float4 be = gb4[g*32 + 16 + sl];
    acc.x = acc.x*(1.f+ga.x) + be.x;
    acc.y = acc.y*(1.f+ga.y) + be.y;
    acc.z = acc.z*(1.f+ga.z) + be.z;
    acc.w = acc.w*(1.f+ga.w) + be.w;
    float4 zc = rowmat16(acc, sl, Wl);
    ((float4*)z1)[i*16 + sl] = zc;
    attn_proj(zc, sl, as1, ad1, i, es1, ed1);
}

__global__ void k_layer2(const int* __restrict__ rowptr, const int* __restrict__ csr_src,
                         const float* __restrict__ es1, const float* __restrict__ ed1,
                         const float* __restrict__ z1, const float* __restrict__ bg1,
                         const int* __restrict__ batch, const float* __restrict__ gb2,
                         const float* __restrict__ Wg2, const float* __restrict__ as2,
                         const float* __restrict__ ad2,
                         float* __restrict__ z2, float* __restrict__ es2,
                         float* __restrict__ ed2) {
    __shared__ float4 Wl[1024];
    const float4* Wg4 = (const float4*)Wg2;
    for (int t = threadIdx.x; t < 1024; t += blockDim.x) Wl[t] = Wg4[t];
    int tid = blockIdx.x * blockDim.x + threadIdx.x;
    int i  = tid >> 4;
    int sl = threadIdx.x & 15;
    __syncthreads();
    if (i >= N_NODES) return;
    float4 o = gat_core(i, sl, rowptr, csr_src, es1, ed1, z1, bg1);
    int g = batch[i];
    const float4* gb4 = (const float4*)gb2;
    float4 ga = gb4[g*32 + sl];
    float4 be = gb4[g*32 + 16 + sl];
    o.x = o.x*(1.f+ga.x) + be.x;
    o.y = o.y*(1.f+ga.y) + be.y;
    o.z = o.z*(1.f+ga.z) + be.z;
    o.w = o.w*(1.f+ga.w) + be.w;
    float4 zc = rowmat16(o, sl, Wl);
    ((float4*)z2)[i*16 + sl] = zc;
    attn_proj(zc, sl, as2, ad2, i, es2, ed2);
}

__global__ void k_layer3(const int* __restrict__ rowptr, const int* __restrict__ csr_src,
                         const float* __restrict__ es2, const float* __restrict__ ed2,
                         const float* __restrict__ z2, const float* __restrict__ bg2,
                         const float* __restrict__ x,
                         const float* __restrict__ Wc1, const float* __restrict__ bc1,
                         const float* __restrict__ Wc2, const float* __restrict__ bc2,
                         const float* __restrict__ Wh1, const float* __restrict__ bh1,
                         const float* __restrict__ Wh2, const float* __restrict__ bh2,
                         float* __restrict__ out) {
    __shared__ float4 Wl[1024];
    const float4* Wc14 = (const float4*)Wc1;
    for (int t = threadIdx.x; t < 1024; t += blockDim.x) Wl[t] = Wc14[t];
    int tid = blockIdx.x * blockDim.x + threadIdx.x;
    int i  = tid >> 4;
    int sl = threadIdx.x & 15;
    __syncthreads();
    if (i >= N_NODES) return;
    float4 o = gat_core(i, sl, rowptr, csr_src, es2, ed2, z2, bg2);
    float4 acc = rowmat16(o, sl, Wl);
    float4 b4 = ((const float4*)bc1)[sl];
    acc.x = fmaxf(acc.x + b4.x, 0.f);
    acc.y = fmaxf(acc.y + b4.y, 0.f);
    acc.z = fmaxf(acc.z + b4.z, 0.f);
    acc.w = fmaxf(acc.w + b4.w, 0.f);
    const float4* Wc24 = (const float4*)Wc2;
    float4 r0 = Wc24[sl*4+0], r1 = Wc24[sl*4+1], r2 = Wc24[sl*4+2], r3 = Wc24[sl*4+3];
    float4 p;
    p.x = acc.x*r0.x + acc.y*r1.x + acc.z*r2.x + acc.w*r3.x;
    p.y = acc.x*r0.y + acc.y*r1.y + acc.z*r2.y + acc.w*r3.y;
    p.z = acc.x*r0.z + acc.y*r1.z + acc.z*r2.z + acc.w*r3.z;
    p.w = acc.x*r0.w + acc.y*r1.w + acc.z*r2.w + acc.w*r3.w;
    #pragma unroll
    for (int off = 1; off < 16; off <<= 1) {
        p.x += __shfl_xor(p.x, off, 16);
        p.y += __shfl_xor(p.y, off, 16);
        p.z += __shfl_xor(p.z, off, 16);
        p.w += __shfl_xor(p.w, off, 16);
    }
    if (sl == 0) {
        float f0 = x[i*8+6], f1 = x[i*8+7];
        float t8[8];
        #pragma unroll
        for (int q = 0; q < 8; q++)
            t8[q] = fmaxf(f0*Wh1[q] + f1*Wh1[8+q] + bh1[q], 0.f);
        float fl[4];
        #pragma unroll
        for (int q = 0; q < 4; q++) {
            float a = bh2[q];
            #pragma unroll
            for (int r = 0; r < 8; r++) a += t8[r]*Wh2[r*4+q];
            fl[q] = a;
        }
        float4 ov;
        ov.x = p.x + bc2[0] + 0.03f*fl[0];
        ov.y = p.y + bc2[1] + 0.03f*fl[1];
        ov.z = p.z + bc2[2] + 0.03f*fl[2];
        ov.w = p.w + bc2[3] + 0.03f*fl[3];
        ((float4*)out)[i] = ov;
    }
}

extern "C" void kernel_launch(void* const* d_in, const int* in_sizes, int n_in,
                              void* d_out, int out_size, void* d_ws, size_t ws_size,
                              hipStream_t stream) {
    const float* x       = (const float*)d_in[0];
    const int*   ei      = (const int*)  d_in[1];
    const int*   batch   = (const int*)  d_in[2];
    const float* climber = (const float*)d_in[3];
    const float* W_in    = (const float*)d_in[4];
    const float* b_in    = (const float*)d_in[5];
    const float* ln_g    = (const float*)d_in[6];
    const float* ln_b    = (const float*)d_in[7];
    const float* W_c     = (const float*)d_in[8];
    const float* b_c     = (const float*)d_in[9];
    const float* Wf1     = (const float*)d_in[10];
    const float* bf1     = (const float*)d_in[11];
    const float* Wf2     = (const float*)d_in[12];
    const float* bf2     = (const float*)d_in[13];
    const float* Wg1     = (const float*)d_in[14];
    const float* as1     = (const float*)d_in[15];
    const float* ad1     = (const float*)d_in[16];
    const float* bg1     = (const float*)d_in[17];
    const float* Wg2     = (const float*)d_in[18];
    const float* as2     = (const float*)d_in[19];
    const float* ad2     = (const float*)d_in[20];
    const float* bg2     = (const float*)d_in[21];
    const float* Wc1     = (const float*)d_in[22];
    const float* bc1     = (const float*)d_in[23];
    const float* Wc2     = (const float*)d_in[24];
    const float* bc2     = (const float*)d_in[25];
    const float* Wh1     = (const float*)d_in[26];
    const float* bh1     = (const float*)d_in[27];
    const float* Wh2     = (const float*)d_in[28];
    const float* bh2     = (const float*)d_in[29];
    float* out = (float*)d_out;
    float* ws  = (float*)d_ws;

    // workspace carve (~69 MB)
    float* c           = ws;                    // 64,000
    float* gb1         = c   + 64000;           // 128,000
    float* gb2         = gb1 + 128000;          // 128,000
    float* z1          = gb2 + 128000;          // 6,400,000
    float* z2          = z1  + 6400000;         // 6,400,000
    float* es1         = z2  + 6400000;         // 100,000
    float* ed1         = es1 + N_NODES;         // 100,000
    float* es2         = ed1 + N_NODES;         // 100,000
    float* ed2         = es2 + N_NODES;         // 100,000
    int*   rowptr      = (int*)(ed2 + N_NODES); // 100,001
    int*   csr_src     = rowptr + N_NODES + 1;  // 1,200,000
    int*   bucket_cnt  = csr_src + N_EDGES;     // 256
    int*   bucket_base = bucket_cnt + NBUCK;    // 257
    int*   bucket_fill = bucket_base + NBUCK+1; // 256
    int2*  staged      = (int2*)(bucket_fill + NBUCK + 1); // 1,200,000 int2

    // CSR build via bucket sort (topology is layer-invariant)
    hipMemsetAsync(bucket_cnt,  0, NBUCK*sizeof(int), stream);
    hipMemsetAsync(bucket_fill, 0, NBUCK*sizeof(int), stream);
    k_bhist<<<S3_BLOCKS, 1024, 0, stream>>>(ei, bucket_cnt);
    k_bscan<<<1, NBUCK, 0, stream>>>(bucket_cnt, bucket_base);
    k_bin  <<<S3_BLOCKS, 1024, 0, stream>>>(ei, bucket_base, bucket_fill, staged);
    k_bcsr <<<NBUCK, 1024, 0, stream>>>(staged, bucket_base, rowptr, csr_src);

    // prologue
    k_climber<<<N_GRAPHS, 64, 0, stream>>>(climber, ln_g, ln_b, W_c, b_c, c);
    dim3 gB(N_GRAPHS, 2);
    k_film_coef<<<gB, 128, 0, stream>>>(c, Wf1, bf1, Wf2, bf2, gb1, gb2);

    int nodeBlocks = (N_NODES*16 + 255)/256;   // 6250
    k_layer1<<<nodeBlocks, 256, 0, stream>>>(x, batch, W_in, b_in, gb1, Wg1,
                                             as1, ad1, z1, es1, ed1);
    k_layer2<<<nodeBlocks, 256, 0, stream>>>(rowptr, csr_src, es1, ed1, z1, bg1,
                                             batch, gb2, Wg2, as2, ad2, z2, es2, ed2);
    k_layer3<<<nodeBlocks, 256, 0, stream>>>(rowptr, csr_src, es2, ed2, z2, bg2,
                                             x, Wc1, bc1, Wc2, bc2,
                                             Wh1, bh1, Wh2, bh2, out);
}

// Round 8
// 321.883 us; speedup vs baseline: 3.9086x; 1.0667x over previous
//
#include <hip/hip_runtime.h>
#include <math.h>

#define N_NODES 100000
#define N_EDGES 1200000
#define N_GRAPHS 1000
#define HID 64
#define NBUCK 256
#define NPB   391            // ceil(100000/256); 256*391 = 100096 >= 100000
#define EDGE_CHUNK 16384
#define S3_BLOCKS ((N_EDGES + EDGE_CHUNK - 1) / EDGE_CHUNK)   // 74

typedef _Float16 half_t;
typedef __attribute__((ext_vector_type(4))) _Float16 half4;

// ---------------- CSR build via 2-level bucket sort --------------------------
// staged entry: (local_dst << 17) | src   (src < 2^17, local_dst < 512)

__global__ void k_bhist(const int* __restrict__ ei, int* __restrict__ bucket_cnt) {
    __shared__ int hist[NBUCK];
    for (int t = threadIdx.x; t < NBUCK; t += blockDim.x) hist[t] = 0;
    __syncthreads();
    int e0 = blockIdx.x * EDGE_CHUNK;
    int e1 = min(e0 + EDGE_CHUNK, N_EDGES);
    for (int e = e0 + threadIdx.x; e < e1; e += blockDim.x)
        atomicAdd(&hist[ei[N_EDGES + e] / NPB], 1);
    __syncthreads();
    for (int t = threadIdx.x; t < NBUCK; t += blockDim.x)
        if (hist[t]) atomicAdd(&bucket_cnt[t], hist[t]);
}

__global__ void k_bscan(const int* __restrict__ bucket_cnt, int* __restrict__ bucket_base) {
    __shared__ int sh[NBUCK];
    int t = threadIdx.x;
    int v = bucket_cnt[t];
    sh[t] = v;
    __syncthreads();
    for (int off = 1; off < NBUCK; off <<= 1) {
        int u = (t >= off) ? sh[t - off] : 0;
        __syncthreads();
        sh[t] += u;
        __syncthreads();
    }
    bucket_base[t] = sh[t] - v;               // exclusive
    if (t == NBUCK - 1) bucket_base[NBUCK] = sh[t];
}

__global__ void k_bin(const int* __restrict__ ei, const int* __restrict__ bucket_base,
                      int* __restrict__ bucket_fill, int* __restrict__ staged) {
    __shared__ int hist[NBUCK];
    __shared__ int cursor[NBUCK];
    for (int t = threadIdx.x; t < NBUCK; t += blockDim.x) hist[t] = 0;
    __syncthreads();
    int e0 = blockIdx.x * EDGE_CHUNK;
    int e1 = min(e0 + EDGE_CHUNK, N_EDGES);
    for (int e = e0 + threadIdx.x; e < e1; e += blockDim.x)
        atomicAdd(&hist[ei[N_EDGES + e] / NPB], 1);
    __syncthreads();
    if (threadIdx.x < NBUCK) {
        int hv = hist[threadIdx.x];
        int start = bucket_base[threadIdx.x];
        if (hv) start += atomicAdd(&bucket_fill[threadIdx.x], hv);
        cursor[threadIdx.x] = start;
    }
    __syncthreads();
    for (int e = e0 + threadIdx.x; e < e1; e += blockDim.x) {
        int src = ei[e], dst = ei[N_EDGES + e];
        int b = dst / NPB;
        int ldst = dst - b * NPB;
        int pos = atomicAdd(&cursor[b], 1);
        staged[pos] = (ldst << 17) | src;
    }
}

__global__ void k_bcsr(const int* __restrict__ staged, const int* __restrict__ bucket_base,
                       int* __restrict__ rowptr, int* __restrict__ csr_src) {
    __shared__ int ldeg[NPB];
    __shared__ int sc[512];
    __shared__ int cursor[NPB];
    int b = blockIdx.x;
    int n0 = b * NPB;
    int n1 = min(n0 + NPB, N_NODES);
    int nn = n1 - n0;
    int bbase = bucket_base[b];
    int bcnt  = bucket_base[b+1] - bbase;
    for (int t = threadIdx.x; t < NPB; t += blockDim.x) ldeg[t] = 0;
    __syncthreads();
    for (int k = threadIdx.x; k < bcnt; k += blockDim.x)
        atomicAdd(&ldeg[staged[bbase + k] >> 17], 1);
    __syncthreads();
    if (threadIdx.x < 512) sc[threadIdx.x] = (threadIdx.x < nn) ? ldeg[threadIdx.x] : 0;
    __syncthreads();
    for (int off = 1; off < 512; off <<= 1) {
        int u = 0;
        if (threadIdx.x < 512 && threadIdx.x >= off) u = sc[threadIdx.x - off];
        __syncthreads();
        if (threadIdx.x < 512) sc[threadIdx.x] += u;
        __syncthreads();
    }
    if (threadIdx.x < nn) {
        int pre = sc[threadIdx.x] - ldeg[threadIdx.x];     // exclusive
        rowptr[n0 + threadIdx.x] = bbase + pre;
        cursor[threadIdx.x] = bbase + pre;
    }
    if (b == 0 && threadIdx.x == 0) rowptr[N_NODES] = bucket_base[NBUCK];
    __syncthreads();
    for (int k = threadIdx.x; k < bcnt; k += blockDim.x) {
        int v = staged[bbase + k];
        int pos = atomicAdd(&cursor[v >> 17], 1);
        csr_src[pos] = v & 0x1FFFF;
    }
}

// ---------------- small dense prologue --------------------------------------

__global__ void k_climber(const float* __restrict__ climber,
                          const float* __restrict__ ln_g, const float* __restrict__ ln_b,
                          const float* __restrict__ W_c, const float* __restrict__ b_c,
                          float* __restrict__ c) {
    int g = blockIdx.x;
    int j = threadIdx.x;
    float v[6];
    float mu = 0.f;
    #pragma unroll
    for (int k = 0; k < 6; k++) { v[k] = climber[g*6+k]; mu += v[k]; }
    mu *= (1.f/6.f);
    float var = 0.f;
    #pragma unroll
    for (int k = 0; k < 6; k++) { float d = v[k]-mu; var += d*d; }
    var *= (1.f/6.f);
    float rs = rsqrtf(var + 1e-5f);
    float acc = b_c[j];
    #pragma unroll
    for (int k = 0; k < 6; k++) {
        float cn = (v[k]-mu)*rs*ln_g[k] + ln_b[k];
        acc += cn * W_c[k*64+j];
    }
    c[g*64+j] = fmaxf(acc, 0.f);
}

__global__ void k_film_coef(const float* __restrict__ c,
                            const float* __restrict__ Wf1, const float* __restrict__ bf1,
                            const float* __restrict__ Wf2, const float* __restrict__ bf2,
                            float* __restrict__ gb1, float* __restrict__ gb2) {
    int g = blockIdx.x;
    const float* Wf = blockIdx.y ? Wf2 : Wf1;
    const float* bf = blockIdx.y ? bf2 : bf1;
    float*       gb = blockIdx.y ? gb2 : gb1;
    int j = threadIdx.x;
    float acc = bf[j];
    #pragma unroll 8
    for (int k = 0; k < 64; k++)
        acc += c[g*64+k] * Wf[k*128+j];
    gb[g*128+j] = acc;
}

// ---------------- fused node kernels ----------------------------------------
// Layout: 4 nodes per wave, 16 lanes/node, lane sl holds features 4sl..4sl+3.
// z stored fp16 (half4 per lane = 128 B/row): halves gather traffic, doubles
// effective L2 reach. Scores es/ed computed from fp32 z before rounding.

__device__ __forceinline__ float4 h4_to_f4(half4 h) {
    float4 f;
    f.x = (float)h.x; f.y = (float)h.y; f.z = (float)h.z; f.w = (float)h.w;
    return f;
}

__device__ __forceinline__ float4 gat_core(int i, int sl,
    const int* __restrict__ rowptr, const int* __restrict__ csr_src,
    const float* __restrict__ es, const float* __restrict__ ed,
    const half_t* __restrict__ z, const float* __restrict__ bg) {
    int beg = rowptr[i], end = rowptr[i+1];
    int deg = end - beg;
    float edi = ed[i];

    float e_self = es[i] + edi;
    e_self = fmaxf(e_self, 0.2f * e_self);

    // cache up to 32 edges: bank A = edges [0,16), bank B = [16,32)
    int svA = 0, svB = 0;
    float scA = -1e30f, scB = -1e30f;
    if (sl < deg) {
        svA = csr_src[beg + sl];
        float v = es[svA] + edi;
        scA = fmaxf(v, 0.2f * v);
    }
    if (16 + sl < deg) {
        svB = csr_src[beg + 16 + sl];
        float v = es[svB] + edi;
        scB = fmaxf(v, 0.2f * v);
    }
    float t = fmaxf(scA, scB);
    for (int k = beg + 32 + sl; k < end; k += 16) {   // rare: deg > 32
        int s2 = csr_src[k];
        float v = es[s2] + edi;
        t = fmaxf(t, fmaxf(v, 0.2f * v));
    }
    #pragma unroll
    for (int off = 1; off < 16; off <<= 1)
        t = fmaxf(t, __shfl_xor(t, off, 16));
    float m = fmaxf(e_self, t);

    const half4* z4 = (const half4*)z;
    float ex = __expf(e_self - m);
    float s = ex;
    float4 zi = h4_to_f4(z4[i*16 + sl]);
    float4 acc = {ex*zi.x, ex*zi.y, ex*zi.z, ex*zi.w};

    int lim = (deg < 32) ? deg : 32;
    int k = 0;
    // unroll-4: four independent row-gathers in flight per step
    for (; k + 4 <= lim; k += 4) {
        int a0, a1, a2, a3;
        float c0, c1, c2, c3;
        if (k < 16) {            // block [k,k+3] fully in bank A
            a0 = __shfl(svA, k+0, 16); c0 = __shfl(scA, k+0, 16);
            a1 = __shfl(svA, k+1, 16); c1 = __shfl(scA, k+1, 16);
            a2 = __shfl(svA, k+2, 16); c2 = __shfl(scA, k+2, 16);
            a3 = __shfl(svA, k+3, 16); c3 = __shfl(scA, k+3, 16);
        } else {
            a0 = __shfl(svB, k-16, 16); c0 = __shfl(scB, k-16, 16);
            a1 = __shfl(svB, k-15, 16); c1 = __shfl(scB, k-15, 16);
            a2 = __shfl(svB, k-14, 16); c2 = __shfl(scB, k-14, 16);
            a3 = __shfl(svB, k-13, 16); c3 = __shfl(scB, k-13, 16);
        }
        half4 q0 = z4[a0*16 + sl];
        half4 q1 = z4[a1*16 + sl];
        half4 q2 = z4[a2*16 + sl];
        half4 q3 = z4[a3*16 + sl];
        float4 r0 = h4_to_f4(q0);
        float4 r1 = h4_to_f4(q1);
        float4 r2 = h4_to_f4(q2);
        float4 r3 = h4_to_f4(q3);
        float e0 = __expf(c0 - m);
        float e1 = __expf(c1 - m);
        float e2 = __expf(c2 - m);
        float e3 = __expf(c3 - m);
        s += (e0 + e1) + (e2 + e3);
        acc.x += e0*r0.x + e1*r1.x + e2*r2.x + e3*r3.x;
        acc.y += e0*r0.y + e1*r1.y + e2*r2.y + e3*r3.y;
        acc.z += e0*r0.z + e1*r1.z + e2*r2.z + e3*r3.z;
        acc.w += e0*r0.w + e1*r1.w + e2*r2.w + e3*r3.w;
    }
    for (; k < lim; k++) {
        int a; float cv;
        if (k < 16) { a = __shfl(svA, k, 16);    cv = __shfl(scA, k, 16); }
        else        { a = __shfl(svB, k-16, 16); cv = __shfl(scB, k-16, 16); }
        float e2 = __expf(cv - m);
        s += e2;
        float4 zr = h4_to_f4(z4[a*16 + sl]);
        acc.x += e2*zr.x; acc.y += e2*zr.y; acc.z += e2*zr.z; acc.w += e2*zr.w;
    }
    for (int kk = beg + 32; kk < end; kk++) {   // rare fallback
        int sv = csr_src[kk];
        float v = es[sv] + edi;
        v = fmaxf(v, 0.2f * v);
        float e2 = __expf(v - m);
        s += e2;
        float4 zr = h4_to_f4(z4[sv*16 + sl]);
        acc.x += e2*zr.x; acc.y += e2*zr.y; acc.z += e2*zr.z; acc.w += e2*zr.w;
    }
    float inv = 1.f / (s + 1e-16f);
    float4 bg4 = ((const float4*)bg)[sl];
    float4 o;
    o.x = fmaxf(acc.x*inv + bg4.x, 0.f);
    o.y = fmaxf(acc.y*inv + bg4.y, 0.f);
    o.z = fmaxf(acc.z*inv + bg4.z, 0.f);
    o.w = fmaxf(acc.w*inv + bg4.w, 0.f);
    return o;
}

__device__ __forceinline__ float4 rowmat16(float4 hr, int sl, const float4* Wl) {
    float hv[4] = {hr.x, hr.y, hr.z, hr.w};
    float4 acc = {0.f, 0.f, 0.f, 0.f};
    #pragma unroll
    for (int k = 0; k < 64; k++) {
        float hk = __shfl(hv[k & 3], k >> 2, 16);
        float4 w = Wl[k*16 + sl];
        acc.x += hk*w.x; acc.y += hk*w.y; acc.z += hk*w.z; acc.w += hk*w.w;
    }
    return acc;
}

__device__ __forceinline__ void attn_proj(float4 zc, int sl,
    const float* __restrict__ a_src, const float* __restrict__ a_dst,
    int i, float* __restrict__ es, float* __restrict__ ed) {
    float4 as4 = ((const float4*)a_src)[sl];
    float4 ad4 = ((const float4*)a_dst)[sl];
    float ps = zc.x*as4.x + zc.y*as4.y + zc.z*as4.z + zc.w*as4.w;
    float pd = zc.x*ad4.x + zc.y*ad4.y + zc.z*ad4.z + zc.w*ad4.w;
    #pragma unroll
    for (int off = 1; off < 16; off <<= 1) {
        ps += __shfl_xor(ps, off, 16);
        pd += __shfl_xor(pd, off, 16);
    }
    if (sl == 0) { es[i] = ps; ed[i] = pd; }
}

__device__ __forceinline__ void store_z_h4(half_t* z, int i, int sl, float4 zc) {
    half4 h;
    h.x = (half_t)zc.x; h.y = (half_t)zc.y; h.z = (half_t)zc.z; h.w = (half_t)zc.w;
    ((half4*)z)[i*16 + sl] = h;
}

__global__ void k_layer1(const float* __restrict__ x, const int* __restrict__ batch,
                         const float* __restrict__ W_in, const float* __restrict__ b_in,
                         const float* __restrict__ gb1, const float* __restrict__ Wg1,
                         const float* __restrict__ as1, const float* __restrict__ ad1,
                         half_t* __restrict__ z1, float* __restrict__ es1,
                         float* __restrict__ ed1) {
    __shared__ float4 Wl[1024];
    const float4* Wg4 = (const float4*)Wg1;
    for (int t = threadIdx.x; t < 1024; t += blockDim.x) Wl[t] = Wg4[t];
    int tid = blockIdx.x * blockDim.x + threadIdx.x;
    int i  = tid >> 4;
    int sl = threadIdx.x & 15;
    __syncthreads();
    if (i >= N_NODES) return;
    float4 acc = ((const float4*)b_in)[sl];
    #pragma unroll
    for (int k = 0; k < 6; k++) {
        float xk = x[i*8+k];
        float4 w = ((const float4*)W_in)[k*16 + sl];
        acc.x += xk*w.x; acc.y += xk*w.y; acc.z += xk*w.z; acc.w += xk*w.w;
    }
    int g = batch[i];
    const float4* gb4 = (const float4*)gb1;
    float4 ga = gb4[g*32 + sl];
    float4 be = gb4[g*32 + 16 + sl];
    acc.x = acc.x*(1.f+ga.x) + be.x;
    acc.y = acc.y*(1.f+ga.y) + be.y;
    acc.z = acc.z*(1.f+ga.z) + be.z;
    acc.w = acc.w*(1.f+ga.w) + be.w;
    float4 zc = rowmat16(acc, sl, Wl);
    store_z_h4(z1, i, sl, zc);
    attn_proj(zc, sl, as1, ad1, i, es1, ed1);
}

__global__ void k_layer2(const int* __restrict__ rowptr, const int* __restrict__ csr_src,
                         const float* __restrict__ es1, const float* __restrict__ ed1,
                         const half_t* __restrict__ z1, const float* __restrict__ bg1,
                         const int* __restrict__ batch, const float* __restrict__ gb2,
                         const float* __restrict__ Wg2, const float* __restrict__ as2,
                         const float* __restrict__ ad2,
                         half_t* __restrict__ z2, float* __restrict__ es2,
                         float* __restrict__ ed2) {
    __shared__ float4 Wl[1024];
    const float4* Wg4 = (const float4*)Wg2;
    for (int t = threadIdx.x; t < 1024; t += blockDim.x) Wl[t] = Wg4[t];
    int tid = blockIdx.x * blockDim.x + threadIdx.x;
    int i  = tid >> 4;
    int sl = threadIdx.x & 15;
    __syncthreads();
    if (i >= N_NODES) return;
    float4 o = gat_core(i, sl, rowptr, csr_src, es1, ed1, z1, bg1);
    int g = batch[i];
    const float4* gb4 = (const float4*)gb2;
    float4 ga = gb4[g*32 + sl];
    float4 be = gb4[g*32 + 16 + sl];
    o.x = o.x*(1.f+ga.x) + be.x;
    o.y = o.y*(1.f+ga.y) + be.y;
    o.z = o.z*(1.f+ga.z) + be.z;
    o.w = o.w*(1.f+ga.w) + be.w;
    float4 zc = rowmat16(o, sl, Wl);
    store_z_h4(z2, i, sl, zc);
    attn_proj(zc, sl, as2, ad2, i, es2, ed2);
}

__global__ void k_layer3(const int* __restrict__ rowptr, const int* __restrict__ csr_src,
                         const float* __restrict__ es2, const float* __restrict__ ed2,
                         const half_t* __restrict__ z2, const float* __restrict__ bg2,
                         const float* __restrict__ x,
                         const float* __restrict__ Wc1, const float* __restrict__ bc1,
                         const float* __restrict__ Wc2, const float* __restrict__ bc2,
                         const float* __restrict__ Wh1, const float* __restrict__ bh1,
                         const float* __restrict__ Wh2, const float* __restrict__ bh2,
                         float* __restrict__ out) {
    __shared__ float4 Wl[1024];
    const float4* Wc14 = (const float4*)Wc1;
    for (int t = threadIdx.x; t < 1024; t += blockDim.x) Wl[t] = Wc14[t];
    int tid = blockIdx.x * blockDim.x + threadIdx.x;
    int i  = tid >> 4;
    int sl = threadIdx.x & 15;
    __syncthreads();
    if (i >= N_NODES) return;
    float4 o = gat_core(i, sl, rowptr, csr_src, es2, ed2, z2, bg2);
    float4 acc = rowmat16(o, sl, Wl);
    float4 b4 = ((const float4*)bc1)[sl];
    acc.x = fmaxf(acc.x + b4.x, 0.f);
    acc.y = fmaxf(acc.y + b4.y, 0.f);
    acc.z = fmaxf(acc.z + b4.z, 0.f);
    acc.w = fmaxf(acc.w + b4.w, 0.f);
    const float4* Wc24 = (const float4*)Wc2;
    float4 r0 = Wc24[sl*4+0], r1 = Wc24[sl*4+1], r2 = Wc24[sl*4+2], r3 = Wc24[sl*4+3];
    float4 p;
    p.x = acc.x*r0.x + acc.y*r1.x + acc.z*r2.x + acc.w*r3.x;
    p.y = acc.x*r0.y + acc.y*r1.y + acc.z*r2.y + acc.w*r3.y;
    p.z = acc.x*r0.z + acc.y*r1.z + acc.z*r2.z + acc.w*r3.z;
    p.w = acc.x*r0.w + acc.y*r1.w + acc.z*r2.w + acc.w*r3.w;
    #pragma unroll
    for (int off = 1; off < 16; off <<= 1) {
        p.x += __shfl_xor(p.x, off, 16);
        p.y += __shfl_xor(p.y, off, 16);
        p.z += __shfl_xor(p.z, off, 16);
        p.w += __shfl_xor(p.w, off, 16);
    }
    if (sl == 0) {
        float f0 = x[i*8+6], f1 = x[i*8+7];
        float t8[8];
        #pragma unroll
        for (int q = 0; q < 8; q++)
            t8[q] = fmaxf(f0*Wh1[q] + f1*Wh1[8+q] + bh1[q], 0.f);
        float fl[4];
        #pragma unroll
        for (int q = 0; q < 4; q++) {
            float a = bh2[q];
            #pragma unroll
            for (int r = 0; r < 8; r++) a += t8[r]*Wh2[r*4+q];
            fl[q] = a;
        }
        float4 ov;
        ov.x = p.x + bc2[0] + 0.03f*fl[0];
        ov.y = p.y + bc2[1] + 0.03f*fl[1];
        ov.z = p.z + bc2[2] + 0.03f*fl[2];
        ov.w = p.w + bc2[3] + 0.03f*fl[3];
        ((float4*)out)[i] = ov;
    }
}

extern "C" void kernel_launch(void* const* d_in, const int* in_sizes, int n_in,
                              void* d_out, int out_size, void* d_ws, size_t ws_size,
                              hipStream_t stream) {
    const float* x       = (const float*)d_in[0];
    const int*   ei      = (const int*)  d_in[1];
    const int*   batch   = (const int*)  d_in[2];
    const float* climber = (const float*)d_in[3];
    const float* W_in    = (const float*)d_in[4];
    const float* b_in    = (const float*)d_in[5];
    const float* ln_g    = (const float*)d_in[6];
    const float* ln_b    = (const float*)d_in[7];
    const float* W_c     = (const float*)d_in[8];
    const float* b_c     = (const float*)d_in[9];
    const float* Wf1     = (const float*)d_in[10];
    const float* bf1     = (const float*)d_in[11];
    const float* Wf2     = (const float*)d_in[12];
    const float* bf2     = (const float*)d_in[13];
    const float* Wg1     = (const float*)d_in[14];
    const float* as1     = (const float*)d_in[15];
    const float* ad1     = (const float*)d_in[16];
    const float* bg1     = (const float*)d_in[17];
    const float* Wg2     = (const float*)d_in[18];
    const float* as2     = (const float*)d_in[19];
    const float* ad2     = (const float*)d_in[20];
    const float* bg2     = (const float*)d_in[21];
    const float* Wc1     = (const float*)d_in[22];
    const float* bc1     = (const float*)d_in[23];
    const float* Wc2     = (const float*)d_in[24];
    const float* bc2     = (const float*)d_in[25];
    const float* Wh1     = (const float*)d_in[26];
    const float* bh1     = (const float*)d_in[27];
    const float* Wh2     = (const float*)d_in[28];
    const float* bh2     = (const float*)d_in[29];
    float* out = (float*)d_out;
    float* ws  = (float*)d_ws;

    // workspace carve (floats)
    float*  c           = ws;                     // 64,000
    float*  gb1         = c   + 64000;            // 128,000
    float*  gb2         = gb1 + 128000;           // 128,000
    half_t* z1          = (half_t*)(gb2 + 128000);// 6.4M halfs = 3.2M floats
    half_t* z2          = z1 + 6400000;           // 6.4M halfs
    float*  es1         = (float*)(z2 + 6400000); // 100,000
    float*  ed1         = es1 + N_NODES;          // 100,000
    float*  es2         = ed1 + N_NODES;          // 100,000
    float*  ed2         = es2 + N_NODES;          // 100,000
    int*    rowptr      = (int*)(ed2 + N_NODES);  // 100,001
    int*    csr_src     = rowptr + N_NODES + 1;   // 1,200,000
    int*    bucket_cnt  = csr_src + N_EDGES;      // 256
    int*    bucket_base = bucket_cnt + NBUCK;     // 257
    int*    bucket_fill = bucket_base + NBUCK+1;  // 256
    int*    staged      = bucket_fill + NBUCK + 1;// 1,200,000

    // CSR build via bucket sort (topology is layer-invariant)
    hipMemsetAsync(bucket_cnt,  0, NBUCK*sizeof(int), stream);
    hipMemsetAsync(bucket_fill, 0, NBUCK*sizeof(int), stream);
    k_bhist<<<S3_BLOCKS, 1024, 0, stream>>>(ei, bucket_cnt);
    k_bscan<<<1, NBUCK, 0, stream>>>(bucket_cnt, bucket_base);
    k_bin  <<<S3_BLOCKS, 1024, 0, stream>>>(ei, bucket_base, bucket_fill, staged);
    k_bcsr <<<NBUCK, 1024, 0, stream>>>(staged, bucket_base, rowptr, csr_src);

    // prologue
    k_climber<<<N_GRAPHS, 64, 0, stream>>>(climber, ln_g, ln_b, W_c, b_c, c);
    dim3 gB(N_GRAPHS, 2);
    k_film_coef<<<gB, 128, 0, stream>>>(c, Wf1, bf1, Wf2, bf2, gb1, gb2);

    int nodeBlocks = (N_NODES*16 + 255)/256;   // 6250
    k_layer1<<<nodeBlocks, 256, 0, stream>>>(x, batch, W_in, b_in, gb1, Wg1,
                                             as1, ad1, z1, es1, ed1);
    k_layer2<<<nodeBlocks, 256, 0, stream>>>(rowptr, csr_src, es1, ed1, z1, bg1,
                                             batch, gb2, Wg2, as2, ad2, z2, es2, ed2);
    k_layer3<<<nodeBlocks, 256, 0, stream>>>(rowptr, csr_src, es2, ed2, z2, bg2,
                                             x, Wc1, bc1, Wc2, bc2,
                                             Wh1, bh1, Wh2, bh2, out);
}

// Round 9
// 319.069 us; speedup vs baseline: 3.9431x; 1.0088x over previous
//
#include <hip/hip_runtime.h>
#include <math.h>

#define N_NODES 100000
#define N_EDGES 1200000
#define N_GRAPHS 1000
#define HID 64
#define NBUCK 256
#define NPB   391            // ceil(100000/256)
#define EDGE_CHUNK 16384
#define S3_BLOCKS ((N_EDGES + EDGE_CHUNK - 1) / EDGE_CHUNK)   // 74
#define LOG2E 1.4426950408889634f

typedef _Float16 half_t;
typedef __attribute__((ext_vector_type(4))) _Float16 half4;

// ---------------- CSR build via 2-level bucket sort --------------------------
// staged entry: (local_dst << 17) | src   (src < 2^17, local_dst < 512)

__global__ void k_bhist(const int* __restrict__ ei, int* __restrict__ bucket_cnt) {
    __shared__ int hist[NBUCK];
    for (int t = threadIdx.x; t < NBUCK; t += blockDim.x) hist[t] = 0;
    __syncthreads();
    int e0 = blockIdx.x * EDGE_CHUNK;
    int e1 = min(e0 + EDGE_CHUNK, N_EDGES);
    for (int e = e0 + threadIdx.x; e < e1; e += blockDim.x)
        atomicAdd(&hist[ei[N_EDGES + e] / NPB], 1);
    __syncthreads();
    for (int t = threadIdx.x; t < NBUCK; t += blockDim.x)
        if (hist[t]) atomicAdd(&bucket_cnt[t], hist[t]);
}

__global__ void k_bscan(const int* __restrict__ bucket_cnt, int* __restrict__ bucket_base) {
    __shared__ int sh[NBUCK];
    int t = threadIdx.x;
    int v = bucket_cnt[t];
    sh[t] = v;
    __syncthreads();
    for (int off = 1; off < NBUCK; off <<= 1) {
        int u = (t >= off) ? sh[t - off] : 0;
        __syncthreads();
        sh[t] += u;
        __syncthreads();
    }
    bucket_base[t] = sh[t] - v;               // exclusive
    if (t == NBUCK - 1) bucket_base[NBUCK] = sh[t];
}

__global__ void k_bin(const int* __restrict__ ei, const int* __restrict__ bucket_base,
                      int* __restrict__ bucket_fill, int* __restrict__ staged) {
    __shared__ int hist[NBUCK];
    __shared__ int cursor[NBUCK];
    for (int t = threadIdx.x; t < NBUCK; t += blockDim.x) hist[t] = 0;
    __syncthreads();
    int e0 = blockIdx.x * EDGE_CHUNK;
    int e1 = min(e0 + EDGE_CHUNK, N_EDGES);
    for (int e = e0 + threadIdx.x; e < e1; e += blockDim.x)
        atomicAdd(&hist[ei[N_EDGES + e] / NPB], 1);
    __syncthreads();
    if (threadIdx.x < NBUCK) {
        int hv = hist[threadIdx.x];
        int start = bucket_base[threadIdx.x];
        if (hv) start += atomicAdd(&bucket_fill[threadIdx.x], hv);
        cursor[threadIdx.x] = start;
    }
    __syncthreads();
    for (int e = e0 + threadIdx.x; e < e1; e += blockDim.x) {
        int src = ei[e], dst = ei[N_EDGES + e];
        int b = dst / NPB;
        int ldst = dst - b * NPB;
        int pos = atomicAdd(&cursor[b], 1);
        staged[pos] = (ldst << 17) | src;
    }
}

__global__ void k_bcsr(const int* __restrict__ staged, const int* __restrict__ bucket_base,
                       int* __restrict__ rowptr, int* __restrict__ csr_src) {
    __shared__ int ldeg[NPB];
    __shared__ int sc[512];
    __shared__ int cursor[NPB];
    int b = blockIdx.x;
    int n0 = b * NPB;
    int n1 = min(n0 + NPB, N_NODES);
    int nn = n1 - n0;
    int bbase = bucket_base[b];
    int bcnt  = bucket_base[b+1] - bbase;
    for (int t = threadIdx.x; t < NPB; t += blockDim.x) ldeg[t] = 0;
    __syncthreads();
    for (int k = threadIdx.x; k < bcnt; k += blockDim.x)
        atomicAdd(&ldeg[staged[bbase + k] >> 17], 1);
    __syncthreads();
    if (threadIdx.x < 512) sc[threadIdx.x] = (threadIdx.x < nn) ? ldeg[threadIdx.x] : 0;
    __syncthreads();
    for (int off = 1; off < 512; off <<= 1) {
        int u = 0;
        if (threadIdx.x < 512 && threadIdx.x >= off) u = sc[threadIdx.x - off];
        __syncthreads();
        if (threadIdx.x < 512) sc[threadIdx.x] += u;
        __syncthreads();
    }
    if (threadIdx.x < nn) {
        int pre = sc[threadIdx.x] - ldeg[threadIdx.x];     // exclusive
        rowptr[n0 + threadIdx.x] = bbase + pre;
        cursor[threadIdx.x] = bbase + pre;
    }
    if (b == 0 && threadIdx.x == 0) rowptr[N_NODES] = bucket_base[NBUCK];
    __syncthreads();
    for (int k = threadIdx.x; k < bcnt; k += blockDim.x) {
        int v = staged[bbase + k];
        int pos = atomicAdd(&cursor[v >> 17], 1);
        csr_src[pos] = v & 0x1FFFF;
    }
}

// ---------------- fused climber LN + FiLM coefficient kernel -----------------
// block = 128: threads 0..63 compute c into LDS; all 128 then compute gb1/gb2.
__global__ void k_climber_film(const float* __restrict__ climber,
                               const float* __restrict__ ln_g, const float* __restrict__ ln_b,
                               const float* __restrict__ W_c, const float* __restrict__ b_c,
                               const float* __restrict__ Wf1, const float* __restrict__ bf1,
                               const float* __restrict__ Wf2, const float* __restrict__ bf2,
                               float* __restrict__ gb1, float* __restrict__ gb2) {
    __shared__ float cl[64];
    int g = blockIdx.x;
    int j = threadIdx.x;
    if (j < 64) {
        float v[6];
        float mu = 0.f;
        #pragma unroll
        for (int k = 0; k < 6; k++) { v[k] = climber[g*6+k]; mu += v[k]; }
        mu *= (1.f/6.f);
        float var = 0.f;
        #pragma unroll
        for (int k = 0; k < 6; k++) { float d = v[k]-mu; var += d*d; }
        var *= (1.f/6.f);
        float rs = rsqrtf(var + 1e-5f);
        float acc = b_c[j];
        #pragma unroll
        for (int k = 0; k < 6; k++) {
            float cn = (v[k]-mu)*rs*ln_g[k] + ln_b[k];
            acc += cn * W_c[k*64+j];
        }
        cl[j] = fmaxf(acc, 0.f);
    }
    __syncthreads();
    float a1 = bf1[j], a2 = bf2[j];
    #pragma unroll 8
    for (int k = 0; k < 64; k++) {
        float ck = cl[k];
        a1 += ck * Wf1[k*128+j];
        a2 += ck * Wf2[k*128+j];
    }
    gb1[g*128+j] = a1;
    gb2[g*128+j] = a2;
}

// ---------------- fused node kernels ----------------------------------------
// Layout: 4 nodes per wave, 16 lanes/node, lane sl holds features 4sl..4sl+3.
// z stored fp16. es/ed pre-scaled by log2(e): leaky-relu and max commute with
// positive scaling, so exp(score diff) == exp2(scaled diff) -> bare v_exp_f32.

__device__ __forceinline__ float4 h4_to_f4(half4 h) {
    float4 f;
    f.x = (float)h.x; f.y = (float)h.y; f.z = (float)h.z; f.w = (float)h.w;
    return f;
}

__device__ __forceinline__ float4 gat_core(int i, int sl,
    const int* __restrict__ rowptr, const int* __restrict__ csr_src,
    const float* __restrict__ es, const float* __restrict__ ed,
    const half_t* __restrict__ z, const float* __restrict__ bg) {
    int beg = rowptr[i], end = rowptr[i+1];
    int deg = end - beg;
    float edi = ed[i];

    float e_self = es[i] + edi;
    e_self = fmaxf(e_self, 0.2f * e_self);

    // cache up to 32 edges: bank A = edges [0,16), bank B = [16,32)
    int svA = 0, svB = 0;
    float scA = -1e30f, scB = -1e30f;
    if (sl < deg) {
        svA = csr_src[beg + sl];
        float v = es[svA] + edi;
        scA = fmaxf(v, 0.2f * v);
    }
    if (16 + sl < deg) {
        svB = csr_src[beg + 16 + sl];
        float v = es[svB] + edi;
        scB = fmaxf(v, 0.2f * v);
    }
    float t = fmaxf(scA, scB);
    for (int k = beg + 32 + sl; k < end; k += 16) {   // rare: deg > 32
        int s2 = csr_src[k];
        float v = es[s2] + edi;
        t = fmaxf(t, fmaxf(v, 0.2f * v));
    }
    #pragma unroll
    for (int off = 1; off < 16; off <<= 1)
        t = fmaxf(t, __shfl_xor(t, off, 16));
    float m = fmaxf(e_self, t);

    const half4* z4 = (const half4*)z;
    float ex = exp2f(e_self - m);
    float s = ex;
    float4 zi = h4_to_f4(z4[i*16 + sl]);
    float4 acc = {ex*zi.x, ex*zi.y, ex*zi.z, ex*zi.w};

    int lim = (deg < 32) ? deg : 32;
    int k = 0;
    // unroll-8: eight independent row-gathers in flight per step.
    // Blocks start at multiples of 8, bank boundary is 16 -> never mixed.
    for (; k + 8 <= lim; k += 8) {
        int a[8]; float c[8];
        if (k < 16) {
            #pragma unroll
            for (int j = 0; j < 8; j++) {
                a[j] = __shfl(svA, k+j, 16);
                c[j] = __shfl(scA, k+j, 16);
            }
        } else {
            #pragma unroll
            for (int j = 0; j < 8; j++) {
                a[j] = __shfl(svB, k-16+j, 16);
                c[j] = __shfl(scB, k-16+j, 16);
            }
        }
        half4 q[8];
        #pragma unroll
        for (int j = 0; j < 8; j++) q[j] = z4[a[j]*16 + sl];
        float e[8];
        #pragma unroll
        for (int j = 0; j < 8; j++) e[j] = exp2f(c[j] - m);
        #pragma unroll
        for (int j = 0; j < 8; j++) {
            float4 r = h4_to_f4(q[j]);
            s += e[j];
            acc.x += e[j]*r.x; acc.y += e[j]*r.y;
            acc.z += e[j]*r.z; acc.w += e[j]*r.w;
        }
    }
    // unroll-4 remainder
    for (; k + 4 <= lim; k += 4) {
        int a[4]; float c[4];
        if (k < 16) {
            #pragma unroll
            for (int j = 0; j < 4; j++) {
                a[j] = __shfl(svA, k+j, 16);
                c[j] = __shfl(scA, k+j, 16);
            }
        } else {
            #pragma unroll
            for (int j = 0; j < 4; j++) {
                a[j] = __shfl(svB, k-16+j, 16);
                c[j] = __shfl(scB, k-16+j, 16);
            }
        }
        half4 q[4];
        #pragma unroll
        for (int j = 0; j < 4; j++) q[j] = z4[a[j]*16 + sl];
        #pragma unroll
        for (int j = 0; j < 4; j++) {
            float e2 = exp2f(c[j] - m);
            float4 r = h4_to_f4(q[j]);
            s += e2;
            acc.x += e2*r.x; acc.y += e2*r.y; acc.z += e2*r.z; acc.w += e2*r.w;
        }
    }
    for (; k < lim; k++) {
        int a; float cv;
        if (k < 16) { a = __shfl(svA, k, 16);    cv = __shfl(scA, k, 16); }
        else        { a = __shfl(svB, k-16, 16); cv = __shfl(scB, k-16, 16); }
        float e2 = exp2f(cv - m);
        s += e2;
        float4 zr = h4_to_f4(z4[a*16 + sl]);
        acc.x += e2*zr.x; acc.y += e2*zr.y; acc.z += e2*zr.z; acc.w += e2*zr.w;
    }
    for (int kk = beg + 32; kk < end; kk++) {   // rare fallback
        int sv = csr_src[kk];
        float v = es[sv] + edi;
        v = fmaxf(v, 0.2f * v);
        float e2 = exp2f(v - m);
        s += e2;
        float4 zr = h4_to_f4(z4[sv*16 + sl]);
        acc.x += e2*zr.x; acc.y += e2*zr.y; acc.z += e2*zr.z; acc.w += e2*zr.w;
    }
    float inv = 1.f / (s + 1e-16f);
    float4 bg4 = ((const float4*)bg)[sl];
    float4 o;
    o.x = fmaxf(acc.x*inv + bg4.x, 0.f);
    o.y = fmaxf(acc.y*inv + bg4.y, 0.f);
    o.z = fmaxf(acc.z*inv + bg4.z, 0.f);
    o.w = fmaxf(acc.w*inv + bg4.w, 0.f);
    return o;
}

__device__ __forceinline__ float4 rowmat16(float4 hr, int sl, const float4* Wl) {
    float hv[4] = {hr.x, hr.y, hr.z, hr.w};
    float4 acc = {0.f, 0.f, 0.f, 0.f};
    #pragma unroll
    for (int k = 0; k < 64; k++) {
        float hk = __shfl(hv[k & 3], k >> 2, 16);
        float4 w = Wl[k*16 + sl];
        acc.x += hk*w.x; acc.y += hk*w.y; acc.z += hk*w.z; acc.w += hk*w.w;
    }
    return acc;
}

// stores es/ed PRE-SCALED by log2(e)
__device__ __forceinline__ void attn_proj(float4 zc, int sl,
    const float* __restrict__ a_src, const float* __restrict__ a_dst,
    int i, float* __restrict__ es, float* __restrict__ ed) {
    float4 as4 = ((const float4*)a_src)[sl];
    float4 ad4 = ((const float4*)a_dst)[sl];
    float ps = zc.x*as4.x + zc.y*as4.y + zc.z*as4.z + zc.w*as4.w;
    float pd = zc.x*ad4.x + zc.y*ad4.y + zc.z*ad4.z + zc.w*ad4.w;
    #pragma unroll
    for (int off = 1; off < 16; off <<= 1) {
        ps += __shfl_xor(ps, off, 16);
        pd += __shfl_xor(pd, off, 16);
    }
    if (sl == 0) { es[i] = ps * LOG2E; ed[i] = pd * LOG2E; }
}

__device__ __forceinline__ void store_z_h4(half_t* z, int i, int sl, float4 zc) {
    half4 h;
    h.x = (half_t)zc.x; h.y = (half_t)zc.y; h.z = (half_t)zc.z; h.w = (half_t)zc.w;
    ((half4*)z)[i*16 + sl] = h;
}

__global__ void k_layer1(const float* __restrict__ x, const int* __restrict__ batch,
                         const float* __restrict__ W_in, const float* __restrict__ b_in,
                         const float* __restrict__ gb1, const float* __restrict__ Wg1,
                         const float* __restrict__ as1, const float* __restrict__ ad1,
                         half_t* __restrict__ z1, float* __restrict__ es1,
                         float* __restrict__ ed1) {
    __shared__ float4 Wl[1024];
    const float4* Wg4 = (const float4*)Wg1;
    for (int t = threadIdx.x; t < 1024; t += blockDim.x) Wl[t] = Wg4[t];
    int tid = blockIdx.x * blockDim.x + threadIdx.x;
    int i  = tid >> 4;
    int sl = threadIdx.x & 15;
    __syncthreads();
    if (i >= N_NODES) return;
    float4 acc = ((const float4*)b_in)[sl];
    #pragma unroll
    for (int k = 0; k < 6; k++) {
        float xk = x[i*8+k];
        float4 w = ((const float4*)W_in)[k*16 + sl];
        acc.x += xk*w.x; acc.y += xk*w.y; acc.z += xk*w.z; acc.w += xk*w.w;
    }
    int g = batch[i];
    const float4* gb4 = (const float4*)gb1;
    float4 ga = gb4[g*32 + sl];
    float4 be = gb4[g*32 + 16 + sl];
    acc.x = acc.x*(1.f+ga.x) + be.x;
    acc.y = acc.y*(1.f+ga.y) + be.y;
    acc.z = acc.z*(1.f+ga.z) + be.z;
    acc.w = acc.w*(1.f+ga.w) + be.w;
    float4 zc = rowmat16(acc, sl, Wl);
    store_z_h4(z1, i, sl, zc);
    attn_proj(zc, sl, as1, ad1, i, es1, ed1);
}

__global__ void k_layer2(const int* __restrict__ rowptr, const int* __restrict__ csr_src,
                         const float* __restrict__ es1, const float* __restrict__ ed1,
                         const half_t* __restrict__ z1, const float* __restrict__ bg1,
                         const int* __restrict__ batch, const float* __restrict__ gb2,
                         const float* __restrict__ Wg2, const float* __restrict__ as2,
                         const float* __restrict__ ad2,
                         half_t* __restrict__ z2, float* __restrict__ es2,
                         float* __restrict__ ed2) {
    __shared__ float4 Wl[1024];
    const float4* Wg4 = (const float4*)Wg2;
    for (int t = threadIdx.x; t < 1024; t += blockDim.x) Wl[t] = Wg4[t];
    int tid = blockIdx.x * blockDim.x + threadIdx.x;
    int i  = tid >> 4;
    int sl = threadIdx.x & 15;
    __syncthreads();
    if (i >= N_NODES) return;
    float4 o = gat_core(i, sl, rowptr, csr_src, es1, ed1, z1, bg1);
    int g = batch[i];
    const float4* gb4 = (const float4*)gb2;
    float4 ga = gb4[g*32 + sl];
    float4 be = gb4[g*32 + 16 + sl];
    o.x = o.x*(1.f+ga.x) + be.x;
    o.y = o.y*(1.f+ga.y) + be.y;
    o.z = o.z*(1.f+ga.z) + be.z;
    o.w = o.w*(1.f+ga.w) + be.w;
    float4 zc = rowmat16(o, sl, Wl);
    store_z_h4(z2, i, sl, zc);
    attn_proj(zc, sl, as2, ad2, i, es2, ed2);
}

__global__ void k_layer3(const int* __restrict__ rowptr, const int* __restrict__ csr_src,
                         const float* __restrict__ es2, const float* __restrict__ ed2,
                         const half_t* __restrict__ z2, const float* __restrict__ bg2,
                         const float* __restrict__ x,
                         const float* __restrict__ Wc1, const float* __restrict__ bc1,
                         const float* __restrict__ Wc2, const float* __restrict__ bc2,
                         const float* __restrict__ Wh1, const float* __restrict__ bh1,
                         const float* __restrict__ Wh2, const float* __restrict__ bh2,
                         float* __restrict__ out) {
    __shared__ float4 Wl[1024];
    const float4* Wc14 = (const float4*)Wc1;
    for (int t = threadIdx.x; t < 1024; t += blockDim.x) Wl[t] = Wc14[t];
    int tid = blockIdx.x * blockDim.x + threadIdx.x;
    int i  = tid >> 4;
    int sl = threadIdx.x & 15;
    __syncthreads();
    if (i >= N_NODES) return;
    float4 o = gat_core(i, sl, rowptr, csr_src, es2, ed2, z2, bg2);
    float4 acc = rowmat16(o, sl, Wl);
    float4 b4 = ((const float4*)bc1)[sl];
    acc.x = fmaxf(acc.x + b4.x, 0.f);
    acc.y = fmaxf(acc.y + b4.y, 0.f);
    acc.z = fmaxf(acc.z + b4.z, 0.f);
    acc.w = fmaxf(acc.w + b4.w, 0.f);
    const float4* Wc24 = (const float4*)Wc2;
    float4 r0 = Wc24[sl*4+0], r1 = Wc24[sl*4+1], r2 = Wc24[sl*4+2], r3 = Wc24[sl*4+3];
    float4 p;
    p.x = acc.x*r0.x + acc.y*r1.x + acc.z*r2.x + acc.w*r3.x;
    p.y = acc.x*r0.y + acc.y*r1.y + acc.z*r2.y + acc.w*r3.y;
    p.z = acc.x*r0.z + acc.y*r1.z + acc.z*r2.z + acc.w*r3.z;
    p.w = acc.x*r0.w + acc.y*r1.w + acc.z*r2.w + acc.w*r3.w;
    #pragma unroll
    for (int off = 1; off < 16; off <<= 1) {
        p.x += __shfl_xor(p.x, off, 16);
        p.y += __shfl_xor(p.y, off, 16);
        p.z += __shfl_xor(p.z, off, 16);
        p.w += __shfl_xor(p.w, off, 16);
    }
    if (sl == 0) {
        float f0 = x[i*8+6], f1 = x[i*8+7];
        float t8[8];
        #pragma unroll
        for (int q = 0; q < 8; q++)
            t8[q] = fmaxf(f0*Wh1[q] + f1*Wh1[8+q] + bh1[q], 0.f);
        float fl[4];
        #pragma unroll
        for (int q = 0; q < 4; q++) {
            float a = bh2[q];
            #pragma unroll
            for (int r = 0; r < 8; r++) a += t8[r]*Wh2[r*4+q];
            fl[q] = a;
        }
        float4 ov;
        ov.x = p.x + bc2[0] + 0.03f*fl[0];
        ov.y = p.y + bc2[1] + 0.03f*fl[1];
        ov.z = p.z + bc2[2] + 0.03f*fl[2];
        ov.w = p.w + bc2[3] + 0.03f*fl[3];
        ((float4*)out)[i] = ov;
    }
}

extern "C" void kernel_launch(void* const* d_in, const int* in_sizes, int n_in,
                              void* d_out, int out_size, void* d_ws, size_t ws_size,
                              hipStream_t stream) {
    const float* x       = (const float*)d_in[0];
    const int*   ei      = (const int*)  d_in[1];
    const int*   batch   = (const int*)  d_in[2];
    const float* climber = (const float*)d_in[3];
    const float* W_in    = (const float*)d_in[4];
    const float* b_in    = (const float*)d_in[5];
    const float* ln_g    = (const float*)d_in[6];
    const float* ln_b    = (const float*)d_in[7];
    const float* W_c     = (const float*)d_in[8];
    const float* b_c     = (const float*)d_in[9];
    const float* Wf1     = (const float*)d_in[10];
    const float* bf1     = (const float*)d_in[11];
    const float* Wf2     = (const float*)d_in[12];
    const float* bf2     = (const float*)d_in[13];
    const float* Wg1     = (const float*)d_in[14];
    const float* as1     = (const float*)d_in[15];
    const float* ad1     = (const float*)d_in[16];
    const float* bg1     = (const float*)d_in[17];
    const float* Wg2     = (const float*)d_in[18];
    const float* as2     = (const float*)d_in[19];
    const float* ad2     = (const float*)d_in[20];
    const float* bg2     = (const float*)d_in[21];
    const float* Wc1     = (const float*)d_in[22];
    const float* bc1     = (const float*)d_in[23];
    const float* Wc2     = (const float*)d_in[24];
    const float* bc2     = (const float*)d_in[25];
    const float* Wh1     = (const float*)d_in[26];
    const float* bh1     = (const float*)d_in[27];
    const float* Wh2     = (const float*)d_in[28];
    const float* bh2     = (const float*)d_in[29];
    float* out = (float*)d_out;
    float* ws  = (float*)d_ws;

    // workspace carve (floats)
    float*  gb1         = ws;                     // 128,000
    float*  gb2         = gb1 + 128000;           // 128,000
    half_t* z1          = (half_t*)(gb2 + 128000);// 6.4M halfs
    half_t* z2          = z1 + 6400000;           // 6.4M halfs
    float*  es1         = (float*)(z2 + 6400000); // 100,000
    float*  ed1         = es1 + N_NODES;          // 100,000
    float*  es2         = ed1 + N_NODES;          // 100,000
    float*  ed2         = es2 + N_NODES;          // 100,000
    int*    rowptr      = (int*)(ed2 + N_NODES);  // 100,001
    int*    csr_src     = rowptr + N_NODES + 1;   // 1,200,000
    int*    bucket_cnt  = csr_src + N_EDGES;      // 256  \ adjacent: one memset
    int*    bucket_fill = bucket_cnt + NBUCK;     // 256  /
    int*    bucket_base = bucket_fill + NBUCK;    // 257
    int*    staged      = bucket_base + NBUCK + 1;// 1,200,000

    // CSR build via bucket sort (topology is layer-invariant)
    hipMemsetAsync(bucket_cnt, 0, 2*NBUCK*sizeof(int), stream);
    k_bhist<<<S3_BLOCKS, 1024, 0, stream>>>(ei, bucket_cnt);
    k_bscan<<<1, NBUCK, 0, stream>>>(bucket_cnt, bucket_base);
    k_bin  <<<S3_BLOCKS, 1024, 0, stream>>>(ei, bucket_base, bucket_fill, staged);
    k_bcsr <<<NBUCK, 1024, 0, stream>>>(staged, bucket_base, rowptr, csr_src);

    // prologue (fused LN + FiLM coefficients)
    k_climber_film<<<N_GRAPHS, 128, 0, stream>>>(climber, ln_g, ln_b, W_c, b_c,
                                                 Wf1, bf1, Wf2, bf2, gb1, gb2);

    int nodeBlocks = (N_NODES*16 + 255)/256;   // 6250
    k_layer1<<<nodeBlocks, 256, 0, stream>>>(x, batch, W_in, b_in, gb1, Wg1,
                                             as1, ad1, z1, es1, ed1);
    k_layer2<<<nodeBlocks, 256, 0, stream>>>(rowptr, csr_src, es1, ed1, z1, bg1,
                                             batch, gb2, Wg2, as2, ad2, z2, es2, ed2);
    k_layer3<<<nodeBlocks, 256, 0, stream>>>(rowptr, csr_src, es2, ed2, z2, bg2,
                                             x, Wc1, bc1, Wc2, bc2,
                                             Wh1, bh1, Wh2, bh2, out);
}